// Round 1
// baseline (1797.961 us; speedup 1.0000x reference)
//
#include <hip/hip_runtime.h>

#define N_NODES 100000
#define N_EDGES 3200000
#define IN_C 128
#define HID_C 64
#define OUT_C 64

// ---------------- degree accumulation (targets), then dis = rsqrt(deg+1) ----
__global__ void deg_kernel(const int* __restrict__ col,
                           const float* __restrict__ ew,
                           float* __restrict__ deg) {
    int e = blockIdx.x * blockDim.x + threadIdx.x;
    if (e < N_EDGES) atomicAdd(&deg[col[e]], ew[e]);
}

__global__ void dis_kernel(float* __restrict__ deg_dis) {
    int i = blockIdx.x * blockDim.x + threadIdx.x;
    if (i < N_NODES) deg_dis[i] = rsqrtf(deg_dis[i] + 1.0f);  // +1 = self-loop
}

__global__ void norm_kernel(const int* __restrict__ ei,
                            const float* __restrict__ ew,
                            const float* __restrict__ dis,
                            float* __restrict__ norm) {
    int e = blockIdx.x * blockDim.x + threadIdx.x;
    if (e < N_EDGES) {
        int r = ei[e];
        int c = ei[N_EDGES + e];
        norm[e] = dis[r] * ew[e] * dis[c];
    }
}

// ---------------- h = x @ W1   [N,128] @ [128,64] ---------------------------
// block = 256 threads, handles 16 rows; W1 fully staged in LDS (32 KB).
__global__ __launch_bounds__(256) void mm1_kernel(const float* __restrict__ x,
                                                  const float* __restrict__ W,
                                                  float* __restrict__ h) {
    __shared__ float xs[16][IN_C];      // 8 KB
    __shared__ float wsm[IN_C][HID_C];  // 32 KB
    int tid = threadIdx.x;
    for (int i = tid; i < IN_C * HID_C; i += 256) wsm[i >> 6][i & 63] = W[i];
    int rowBase = blockIdx.x * 16;
    for (int i = tid; i < 16 * IN_C; i += 256) {
        int r = i >> 7, k = i & 127;
        xs[r][k] = x[(rowBase + r) * IN_C + k];
    }
    __syncthreads();
    int c = tid & 63, rg = tid >> 6;  // wave-uniform rg -> xs reads broadcast
    float a0 = 0.f, a1 = 0.f, a2 = 0.f, a3 = 0.f;
    for (int k = 0; k < IN_C; ++k) {
        float wv = wsm[k][c];
        a0 += xs[rg * 4 + 0][k] * wv;
        a1 += xs[rg * 4 + 1][k] * wv;
        a2 += xs[rg * 4 + 2][k] * wv;
        a3 += xs[rg * 4 + 3][k] * wv;
    }
    h[(rowBase + rg * 4 + 0) * HID_C + c] = a0;
    h[(rowBase + rg * 4 + 1) * HID_C + c] = a1;
    h[(rowBase + rg * 4 + 2) * HID_C + c] = a2;
    h[(rowBase + rg * 4 + 3) * HID_C + c] = a3;
}

// ---------------- h2 = a @ W2   [N,64] @ [64,64] ----------------------------
__global__ __launch_bounds__(256) void mm2_kernel(const float* __restrict__ a,
                                                  const float* __restrict__ W,
                                                  float* __restrict__ h) {
    __shared__ float as[16][HID_C];      // 4 KB
    __shared__ float wsm[HID_C][OUT_C];  // 16 KB
    int tid = threadIdx.x;
    for (int i = tid; i < HID_C * OUT_C; i += 256) wsm[i >> 6][i & 63] = W[i];
    int rowBase = blockIdx.x * 16;
    for (int i = tid; i < 16 * HID_C; i += 256) {
        int r = i >> 6, k = i & 63;
        as[r][k] = a[(rowBase + r) * HID_C + k];
    }
    __syncthreads();
    int c = tid & 63, rg = tid >> 6;
    float a0 = 0.f, a1 = 0.f, a2 = 0.f, a3 = 0.f;
    for (int k = 0; k < HID_C; ++k) {
        float wv = wsm[k][c];
        a0 += as[rg * 4 + 0][k] * wv;
        a1 += as[rg * 4 + 1][k] * wv;
        a2 += as[rg * 4 + 2][k] * wv;
        a3 += as[rg * 4 + 3][k] * wv;
    }
    h[(rowBase + rg * 4 + 0) * OUT_C + c] = a0;
    h[(rowBase + rg * 4 + 1) * OUT_C + c] = a1;
    h[(rowBase + rg * 4 + 2) * OUT_C + c] = a2;
    h[(rowBase + rg * 4 + 3) * OUT_C + c] = a3;
}

// ---------------- edge scatter: agg[col] += norm * h[row] -------------------
// one 64-lane wave per edge, lane = channel; row/col/norm are wave-uniform.
__global__ __launch_bounds__(256) void scatter_kernel(const int* __restrict__ ei,
                                                      const float* __restrict__ norm,
                                                      const float* __restrict__ h,
                                                      float* __restrict__ agg) {
    int idx = blockIdx.x * blockDim.x + threadIdx.x;  // < 204.8M, fits int32
    int e = idx >> 6;
    if (e < N_EDGES) {
        int c = idx & 63;
        int r = ei[e];
        int t = ei[N_EDGES + e];
        atomicAdd(&agg[t * 64 + c], h[r * 64 + c] * norm[e]);
    }
}

// ---------------- epilogue layer1: self-loop + bias + relu ------------------
__global__ void post1_kernel(float* __restrict__ agg,
                             const float* __restrict__ h,
                             const float* __restrict__ dis,
                             const float* __restrict__ b) {
    int idx = blockIdx.x * blockDim.x + threadIdx.x;
    if (idx < N_NODES * 64) {
        int i = idx >> 6, c = idx & 63;
        float d = dis[i];
        float v = agg[idx] + d * d * h[idx] + b[c];
        agg[idx] = fmaxf(v, 0.0f);
    }
}

// ---------------- epilogue layer2: self-loop + bias (no relu) ---------------
__global__ void post2_kernel(float* __restrict__ out,
                             const float* __restrict__ h,
                             const float* __restrict__ dis,
                             const float* __restrict__ b) {
    int idx = blockIdx.x * blockDim.x + threadIdx.x;
    if (idx < N_NODES * 64) {
        int i = idx >> 6, c = idx & 63;
        float d = dis[i];
        out[idx] = out[idx] + d * d * h[idx] + b[c];
    }
}

extern "C" void kernel_launch(void* const* d_in, const int* in_sizes, int n_in,
                              void* d_out, int out_size, void* d_ws, size_t ws_size,
                              hipStream_t stream) {
    const float* x  = (const float*)d_in[0];
    const int*   ei = (const int*)d_in[1];   // [2, E] row-major: sources then targets
    const float* ew = (const float*)d_in[2];
    const float* W1 = (const float*)d_in[3];
    const float* b1 = (const float*)d_in[4];
    const float* W2 = (const float*)d_in[5];
    const float* b2 = (const float*)d_in[6];
    float* out = (float*)d_out;

    // workspace carve-up (256B aligned chunks)
    char* ws = (char*)d_ws;
    float* dis  = (float*)ws;                                   // N floats (deg then dis)
    float* norm = (float*)(ws + ((N_NODES * 4 + 255) & ~255));  // E floats
    char*  p2   = (char*)norm + ((N_EDGES * 4 + 255) & ~255);
    float* h    = (float*)p2;                                   // N*64 floats
    float* agg  = (float*)(p2 + ((N_NODES * 64 * 4 + 255) & ~255));

    const int TB = 256;
    // --- norm pipeline ---
    hipMemsetAsync(dis, 0, N_NODES * sizeof(float), stream);
    deg_kernel<<<(N_EDGES + TB - 1) / TB, TB, 0, stream>>>(ei + N_EDGES, ew, dis);
    dis_kernel<<<(N_NODES + TB - 1) / TB, TB, 0, stream>>>(dis);
    norm_kernel<<<(N_EDGES + TB - 1) / TB, TB, 0, stream>>>(ei, ew, dis, norm);

    // --- layer 1 ---
    mm1_kernel<<<N_NODES / 16, TB, 0, stream>>>(x, W1, h);
    hipMemsetAsync(agg, 0, (size_t)N_NODES * 64 * sizeof(float), stream);
    scatter_kernel<<<(N_EDGES * 64) / TB, TB, 0, stream>>>(ei, norm, h, agg);
    post1_kernel<<<(N_NODES * 64 + TB - 1) / TB, TB, 0, stream>>>(agg, h, dis, b1);

    // --- layer 2 ---
    mm2_kernel<<<N_NODES / 16, TB, 0, stream>>>(agg, W2, h);
    hipMemsetAsync(out, 0, (size_t)N_NODES * 64 * sizeof(float), stream);
    scatter_kernel<<<(N_EDGES * 64) / TB, TB, 0, stream>>>(ei, norm, h, out);
    post2_kernel<<<(N_NODES * 64 + TB - 1) / TB, TB, 0, stream>>>(out, h, dis, b2);
}

// Round 2
// 920.571 us; speedup vs baseline: 1.9531x; 1.9531x over previous
//
#include <hip/hip_runtime.h>

#define N_NODES 100000
#define N_EDGES 3200000
#define IN_C 128
#define HID_C 64
#define OUT_C 64
#define NBLK 391   // ceil(N_NODES/256)

struct EdgeRec { int s; float v; };   // source node, w*dis[src]

// ---- fused histogram (counts per target) + weighted degree --------------
__global__ void hist_kernel(const int* __restrict__ ei,
                            const float* __restrict__ ew,
                            int* __restrict__ cnt,
                            float* __restrict__ deg) {
    int e = blockIdx.x * blockDim.x + threadIdx.x;
    if (e < N_EDGES) {
        int t = ei[N_EDGES + e];
        atomicAdd(&cnt[t], 1);
        atomicAdd(&deg[t], ew[e]);
    }
}

__global__ void dis_kernel(float* __restrict__ deg_dis) {
    int i = blockIdx.x * blockDim.x + threadIdx.x;
    if (i < N_NODES) deg_dis[i] = rsqrtf(deg_dis[i] + 1.0f);  // +1 = self-loop
}

// ---- 3-kernel exclusive scan of cnt -> rowptr ---------------------------
__global__ __launch_bounds__(256) void scan1_kernel(const int* __restrict__ cnt,
                                                    int* __restrict__ rowptr,
                                                    int* __restrict__ partials) {
    __shared__ int s[256];
    int i = blockIdx.x * 256 + threadIdx.x;
    int v = (i < N_NODES) ? cnt[i] : 0;
    s[threadIdx.x] = v;
    __syncthreads();
    for (int off = 1; off < 256; off <<= 1) {
        int t = s[threadIdx.x];
        int add = (threadIdx.x >= off) ? s[threadIdx.x - off] : 0;
        __syncthreads();
        s[threadIdx.x] = t + add;
        __syncthreads();
    }
    if (i < N_NODES) rowptr[i] = s[threadIdx.x] - v;  // exclusive within block
    if (threadIdx.x == 255) partials[blockIdx.x] = s[255];
}

__global__ __launch_bounds__(512) void scan2_kernel(int* __restrict__ partials) {
    __shared__ int s[512];
    int v = (threadIdx.x < NBLK) ? partials[threadIdx.x] : 0;
    s[threadIdx.x] = v;
    __syncthreads();
    for (int off = 1; off < 512; off <<= 1) {
        int t = s[threadIdx.x];
        int add = (threadIdx.x >= off) ? s[threadIdx.x - off] : 0;
        __syncthreads();
        s[threadIdx.x] = t + add;
        __syncthreads();
    }
    if (threadIdx.x < NBLK) partials[threadIdx.x] = s[threadIdx.x] - v;  // exclusive
}

__global__ __launch_bounds__(256) void scan3_kernel(int* __restrict__ rowptr,
                                                    const int* __restrict__ partials,
                                                    int* __restrict__ cursor) {
    int i = blockIdx.x * 256 + threadIdx.x;
    if (i < N_NODES) {
        int rp = rowptr[i] + partials[blockIdx.x];
        rowptr[i] = rp;
        cursor[i] = rp;
    }
    if (i == 0) rowptr[N_NODES] = N_EDGES;
}

// ---- fill CSR: scatter edges into target-sorted order -------------------
__global__ void fill_kernel(const int* __restrict__ ei,
                            const float* __restrict__ ew,
                            const float* __restrict__ dis,
                            int* __restrict__ cursor,
                            EdgeRec* __restrict__ ed) {
    int e = blockIdx.x * blockDim.x + threadIdx.x;
    if (e < N_EDGES) {
        int r = ei[e];
        int t = ei[N_EDGES + e];
        int pos = atomicAdd(&cursor[t], 1);
        EdgeRec rec;
        rec.s = r;
        rec.v = ew[e] * dis[r];
        ed[pos] = rec;
    }
}

// ---- h = x @ W1   [N,128] @ [128,64] ------------------------------------
__global__ __launch_bounds__(256) void mm1_kernel(const float* __restrict__ x,
                                                  const float* __restrict__ W,
                                                  float* __restrict__ h) {
    __shared__ float xs[16][IN_C];      // 8 KB
    __shared__ float wsm[IN_C][HID_C];  // 32 KB
    int tid = threadIdx.x;
    for (int i = tid; i < IN_C * HID_C; i += 256) wsm[i >> 6][i & 63] = W[i];
    int rowBase = blockIdx.x * 16;
    for (int i = tid; i < 16 * IN_C; i += 256) {
        int r = i >> 7, k = i & 127;
        xs[r][k] = x[(rowBase + r) * IN_C + k];
    }
    __syncthreads();
    int c = tid & 63, rg = tid >> 6;
    float a0 = 0.f, a1 = 0.f, a2 = 0.f, a3 = 0.f;
    for (int k = 0; k < IN_C; ++k) {
        float wv = wsm[k][c];
        a0 += xs[rg * 4 + 0][k] * wv;
        a1 += xs[rg * 4 + 1][k] * wv;
        a2 += xs[rg * 4 + 2][k] * wv;
        a3 += xs[rg * 4 + 3][k] * wv;
    }
    h[(rowBase + rg * 4 + 0) * HID_C + c] = a0;
    h[(rowBase + rg * 4 + 1) * HID_C + c] = a1;
    h[(rowBase + rg * 4 + 2) * HID_C + c] = a2;
    h[(rowBase + rg * 4 + 3) * HID_C + c] = a3;
}

// ---- h2 = a @ W2   [N,64] @ [64,64] -------------------------------------
__global__ __launch_bounds__(256) void mm2_kernel(const float* __restrict__ a,
                                                  const float* __restrict__ W,
                                                  float* __restrict__ h) {
    __shared__ float as[16][HID_C];      // 4 KB
    __shared__ float wsm[HID_C][OUT_C];  // 16 KB
    int tid = threadIdx.x;
    for (int i = tid; i < HID_C * OUT_C; i += 256) wsm[i >> 6][i & 63] = W[i];
    int rowBase = blockIdx.x * 16;
    for (int i = tid; i < 16 * HID_C; i += 256) {
        int r = i >> 6, k = i & 63;
        as[r][k] = a[(rowBase + r) * HID_C + k];
    }
    __syncthreads();
    int c = tid & 63, rg = tid >> 6;
    float a0 = 0.f, a1 = 0.f, a2 = 0.f, a3 = 0.f;
    for (int k = 0; k < HID_C; ++k) {
        float wv = wsm[k][c];
        a0 += as[rg * 4 + 0][k] * wv;
        a1 += as[rg * 4 + 1][k] * wv;
        a2 += as[rg * 4 + 2][k] * wv;
        a3 += as[rg * 4 + 3][k] * wv;
    }
    h[(rowBase + rg * 4 + 0) * OUT_C + c] = a0;
    h[(rowBase + rg * 4 + 1) * OUT_C + c] = a1;
    h[(rowBase + rg * 4 + 2) * OUT_C + c] = a2;
    h[(rowBase + rg * 4 + 3) * OUT_C + c] = a3;
}

// ---- CSR aggregate + fused epilogue -------------------------------------
// one 64-lane wave per target node, lane = channel. No atomics.
// out[t][c] = act( dis[t]*sum_e(v_e*h[s_e][c]) + dis[t]^2*h[t][c] + b[c] )
__global__ __launch_bounds__(256) void agg_kernel(const int* __restrict__ rowptr,
                                                  const EdgeRec* __restrict__ ed,
                                                  const float* __restrict__ h,
                                                  const float* __restrict__ dis,
                                                  const float* __restrict__ b,
                                                  float* __restrict__ out,
                                                  int relu) {
    int node = blockIdx.x * 4 + (threadIdx.x >> 6);
    if (node >= N_NODES) return;
    int c = threadIdx.x & 63;
    int beg = rowptr[node];
    int end = rowptr[node + 1];
    float acc = 0.f;
    int e = beg;
    for (; e + 3 < end; e += 4) {
        EdgeRec r0 = ed[e], r1 = ed[e + 1], r2 = ed[e + 2], r3 = ed[e + 3];
        acc += r0.v * h[r0.s * 64 + c];
        acc += r1.v * h[r1.s * 64 + c];
        acc += r2.v * h[r2.s * 64 + c];
        acc += r3.v * h[r3.s * 64 + c];
    }
    for (; e < end; ++e) {
        EdgeRec r0 = ed[e];
        acc += r0.v * h[r0.s * 64 + c];
    }
    float d = dis[node];
    float v = d * acc + d * d * h[node * 64 + c] + b[c];
    out[node * 64 + c] = relu ? fmaxf(v, 0.0f) : v;
}

extern "C" void kernel_launch(void* const* d_in, const int* in_sizes, int n_in,
                              void* d_out, int out_size, void* d_ws, size_t ws_size,
                              hipStream_t stream) {
    const float* x  = (const float*)d_in[0];
    const int*   ei = (const int*)d_in[1];   // [2, E]: sources then targets
    const float* ew = (const float*)d_in[2];
    const float* W1 = (const float*)d_in[3];
    const float* b1 = (const float*)d_in[4];
    const float* W2 = (const float*)d_in[5];
    const float* b2 = (const float*)d_in[6];
    float* out = (float*)d_out;

    // workspace carve-up (256 B aligned)
    char* p = (char*)d_ws;
    auto carve = [&](size_t bytes) { char* r = p; p += (bytes + 255) & ~(size_t)255; return r; };
    int*     cnt      = (int*)carve(N_NODES * 4);
    float*   dis      = (float*)carve(N_NODES * 4);       // deg then dis, in place
    int*     rowptr   = (int*)carve((N_NODES + 1) * 4);
    int*     cursor   = (int*)carve(N_NODES * 4);
    int*     partials = (int*)carve(512 * 4);
    EdgeRec* ed       = (EdgeRec*)carve((size_t)N_EDGES * 8);
    float*   h        = (float*)carve((size_t)N_NODES * 64 * 4);
    float*   a        = (float*)carve((size_t)N_NODES * 64 * 4);

    const int TB = 256;
    // --- CSR build + norm precompute ---
    hipMemsetAsync(cnt, 0, N_NODES * sizeof(int), stream);
    hipMemsetAsync(dis, 0, N_NODES * sizeof(float), stream);
    hist_kernel<<<(N_EDGES + TB - 1) / TB, TB, 0, stream>>>(ei, ew, cnt, dis);
    dis_kernel<<<(N_NODES + TB - 1) / TB, TB, 0, stream>>>(dis);
    scan1_kernel<<<NBLK, 256, 0, stream>>>(cnt, rowptr, partials);
    scan2_kernel<<<1, 512, 0, stream>>>(partials);
    scan3_kernel<<<NBLK, 256, 0, stream>>>(rowptr, partials, cursor);
    fill_kernel<<<(N_EDGES + TB - 1) / TB, TB, 0, stream>>>(ei, ew, dis, cursor, ed);

    // --- layer 1: h = x@W1 ; a = relu(agg(h) + b1) ---
    mm1_kernel<<<N_NODES / 16, TB, 0, stream>>>(x, W1, h);
    agg_kernel<<<N_NODES / 4, TB, 0, stream>>>(rowptr, ed, h, dis, b1, a, 1);

    // --- layer 2: h = a@W2 ; out = agg(h) + b2 ---
    mm2_kernel<<<N_NODES / 16, TB, 0, stream>>>(a, W2, h);
    agg_kernel<<<N_NODES / 4, TB, 0, stream>>>(rowptr, ed, h, dis, b2, out, 0);
}

// Round 3
// 664.944 us; speedup vs baseline: 2.7039x; 1.3844x over previous
//
#include <hip/hip_runtime.h>

#define N_NODES 100000
#define N_EDGES 3200000
#define IN_C 128
#define HID_C 64
#define OUT_C 64

#define NBUCKET 196          // ceil(N_NODES / 512); bucket = target >> 9
#define CH_GRID 1563         // ceil(E / 2048) for coarse hist (256 thr x 8 edges)
#define SC_GRID 782          // ceil(E / 4096) for coarse scatter (256 thr x 16 edges)

struct EdgeRec { int s; float v; };   // source node, weight (later w*dis[src])

// ---- coarse histogram: count edges per 512-node bucket -------------------
__global__ __launch_bounds__(256) void coarse_hist(const int* __restrict__ tgt,
                                                   int* __restrict__ gcnt) {
    __shared__ int hist[256];
    int tid = threadIdx.x;
    hist[tid] = 0;
    __syncthreads();
    int base = blockIdx.x * 2048;
    for (int i = 0; i < 8; ++i) {
        int e = base + i * 256 + tid;
        if (e < N_EDGES) atomicAdd(&hist[tgt[e] >> 9], 1);
    }
    __syncthreads();
    if (hist[tid]) atomicAdd(&gcnt[tid], hist[tid]);
}

// ---- exclusive scan of 256 bucket counts (single block) ------------------
__global__ __launch_bounds__(256) void coarse_scan(const int* __restrict__ gcnt,
                                                   int* __restrict__ start,
                                                   int* __restrict__ cursor) {
    __shared__ int s[256];
    int tid = threadIdx.x;
    int v = gcnt[tid];
    s[tid] = v;
    __syncthreads();
    for (int off = 1; off < 256; off <<= 1) {
        int t = s[tid];
        int add = (tid >= off) ? s[tid - off] : 0;
        __syncthreads();
        s[tid] = t + add;
        __syncthreads();
    }
    int excl = s[tid] - v;
    start[tid] = excl;
    cursor[tid] = excl;
    if (tid == 255) start[256] = s[255];   // == N_EDGES
}

// ---- coarse scatter: edges -> bucket-major order (block range reservation)
__global__ __launch_bounds__(256) void scatter_coarse(const int* __restrict__ ei,
                                                      const float* __restrict__ ew,
                                                      int* __restrict__ gcursor,
                                                      EdgeRec* __restrict__ tmp_sw,
                                                      int* __restrict__ tmp_t) {
    __shared__ int hist[256];
    __shared__ int blockBase[256];
    __shared__ int lcur[256];
    int tid = threadIdx.x;
    hist[tid] = 0;
    __syncthreads();
    int base = blockIdx.x * 4096;
    int ts[16];
    for (int i = 0; i < 16; ++i) {
        int e = base + i * 256 + tid;
        if (e < N_EDGES) {
            int t = ei[N_EDGES + e];
            ts[i] = t;
            atomicAdd(&hist[t >> 9], 1);
        } else ts[i] = -1;
    }
    __syncthreads();
    blockBase[tid] = atomicAdd(&gcursor[tid], hist[tid]);
    lcur[tid] = 0;
    __syncthreads();
    for (int i = 0; i < 16; ++i) {
        if (ts[i] >= 0) {
            int e = base + i * 256 + tid;
            int b = ts[i] >> 9;
            int off = atomicAdd(&lcur[b], 1);
            int pos = blockBase[b] + off;
            EdgeRec r;
            r.s = ei[e];
            r.v = ew[e];
            tmp_sw[pos] = r;
            tmp_t[pos] = ts[i];
        }
    }
}

// ---- per-bucket counting sort + rowptr + dis (one block per bucket) ------
__global__ __launch_bounds__(512) void fine_sort(const int* __restrict__ start,
                                                 const EdgeRec* __restrict__ tmp_sw,
                                                 const int* __restrict__ tmp_t,
                                                 int* __restrict__ rowptr,
                                                 float* __restrict__ dis,
                                                 EdgeRec* __restrict__ ed) {
    __shared__ int   cnt[512];
    __shared__ float wdeg[512];
    __shared__ int   s[512];
    int tid = threadIdx.x;
    int nodeBase = blockIdx.x << 9;
    int bb = start[blockIdx.x];
    int be = start[blockIdx.x + 1];
    cnt[tid] = 0;
    wdeg[tid] = 0.f;
    __syncthreads();
    for (int e = bb + tid; e < be; e += 512) {
        int l = tmp_t[e] - nodeBase;
        atomicAdd(&cnt[l], 1);
        atomicAdd(&wdeg[l], tmp_sw[e].v);
    }
    __syncthreads();
    int v = cnt[tid];
    s[tid] = v;
    __syncthreads();
    for (int off = 1; off < 512; off <<= 1) {
        int t = s[tid];
        int add = (tid >= off) ? s[tid - off] : 0;
        __syncthreads();
        s[tid] = t + add;
        __syncthreads();
    }
    int excl = s[tid] - v;
    int node = nodeBase + tid;
    if (node < N_NODES) {
        rowptr[node] = bb + excl;
        dis[node] = rsqrtf(wdeg[tid] + 1.0f);   // +1 = self-loop weight
    }
    if (node == N_NODES) rowptr[N_NODES] = N_EDGES;
    cnt[tid] = excl;       // reuse as cursor
    __syncthreads();
    for (int e = bb + tid; e < be; e += 512) {
        int t = tmp_t[e];
        int l = t - nodeBase;
        int p = atomicAdd(&cnt[l], 1);
        ed[bb + p] = tmp_sw[e];
    }
}

// ---- fold dis[src] into edge values --------------------------------------
__global__ void fixup_kernel(EdgeRec* __restrict__ ed,
                             const float* __restrict__ dis) {
    int e = blockIdx.x * blockDim.x + threadIdx.x;
    if (e < N_EDGES) {
        EdgeRec r = ed[e];
        ed[e].v = r.v * dis[r.s];
    }
}

// ---- h = x @ W1   [N,128] @ [128,64] ------------------------------------
__global__ __launch_bounds__(256) void mm1_kernel(const float* __restrict__ x,
                                                  const float* __restrict__ W,
                                                  float* __restrict__ h) {
    __shared__ float xs[16][IN_C];      // 8 KB
    __shared__ float wsm[IN_C][HID_C];  // 32 KB
    int tid = threadIdx.x;
    for (int i = tid; i < IN_C * HID_C; i += 256) wsm[i >> 6][i & 63] = W[i];
    int rowBase = blockIdx.x * 16;
    for (int i = tid; i < 16 * IN_C; i += 256) {
        int r = i >> 7, k = i & 127;
        xs[r][k] = x[(rowBase + r) * IN_C + k];
    }
    __syncthreads();
    int c = tid & 63, rg = tid >> 6;
    float a0 = 0.f, a1 = 0.f, a2 = 0.f, a3 = 0.f;
    for (int k = 0; k < IN_C; ++k) {
        float wv = wsm[k][c];
        a0 += xs[rg * 4 + 0][k] * wv;
        a1 += xs[rg * 4 + 1][k] * wv;
        a2 += xs[rg * 4 + 2][k] * wv;
        a3 += xs[rg * 4 + 3][k] * wv;
    }
    h[(rowBase + rg * 4 + 0) * HID_C + c] = a0;
    h[(rowBase + rg * 4 + 1) * HID_C + c] = a1;
    h[(rowBase + rg * 4 + 2) * HID_C + c] = a2;
    h[(rowBase + rg * 4 + 3) * HID_C + c] = a3;
}

// ---- h2 = a @ W2   [N,64] @ [64,64] -------------------------------------
__global__ __launch_bounds__(256) void mm2_kernel(const float* __restrict__ a,
                                                  const float* __restrict__ W,
                                                  float* __restrict__ h) {
    __shared__ float as[16][HID_C];      // 4 KB
    __shared__ float wsm[HID_C][OUT_C];  // 16 KB
    int tid = threadIdx.x;
    for (int i = tid; i < HID_C * OUT_C; i += 256) wsm[i >> 6][i & 63] = W[i];
    int rowBase = blockIdx.x * 16;
    for (int i = tid; i < 16 * HID_C; i += 256) {
        int r = i >> 6, k = i & 63;
        as[r][k] = a[(rowBase + r) * HID_C + k];
    }
    __syncthreads();
    int c = tid & 63, rg = tid >> 6;
    float a0 = 0.f, a1 = 0.f, a2 = 0.f, a3 = 0.f;
    for (int k = 0; k < HID_C; ++k) {
        float wv = wsm[k][c];
        a0 += as[rg * 4 + 0][k] * wv;
        a1 += as[rg * 4 + 1][k] * wv;
        a2 += as[rg * 4 + 2][k] * wv;
        a3 += as[rg * 4 + 3][k] * wv;
    }
    h[(rowBase + rg * 4 + 0) * OUT_C + c] = a0;
    h[(rowBase + rg * 4 + 1) * OUT_C + c] = a1;
    h[(rowBase + rg * 4 + 2) * OUT_C + c] = a2;
    h[(rowBase + rg * 4 + 3) * OUT_C + c] = a3;
}

// ---- CSR aggregate + fused epilogue (one wave per node, lane=channel) ----
__global__ __launch_bounds__(256) void agg_kernel(const int* __restrict__ rowptr,
                                                  const EdgeRec* __restrict__ ed,
                                                  const float* __restrict__ h,
                                                  const float* __restrict__ dis,
                                                  const float* __restrict__ b,
                                                  float* __restrict__ out,
                                                  int relu) {
    int node = blockIdx.x * 4 + (threadIdx.x >> 6);
    if (node >= N_NODES) return;
    int c = threadIdx.x & 63;
    int beg = rowptr[node];
    int end = rowptr[node + 1];
    float acc = 0.f;
    int e = beg;
    for (; e + 3 < end; e += 4) {
        EdgeRec r0 = ed[e], r1 = ed[e + 1], r2 = ed[e + 2], r3 = ed[e + 3];
        acc += r0.v * h[r0.s * 64 + c];
        acc += r1.v * h[r1.s * 64 + c];
        acc += r2.v * h[r2.s * 64 + c];
        acc += r3.v * h[r3.s * 64 + c];
    }
    for (; e < end; ++e) {
        EdgeRec r0 = ed[e];
        acc += r0.v * h[r0.s * 64 + c];
    }
    float d = dis[node];
    float v = d * acc + d * d * h[node * 64 + c] + b[c];
    out[node * 64 + c] = relu ? fmaxf(v, 0.0f) : v;
}

extern "C" void kernel_launch(void* const* d_in, const int* in_sizes, int n_in,
                              void* d_out, int out_size, void* d_ws, size_t ws_size,
                              hipStream_t stream) {
    const float* x  = (const float*)d_in[0];
    const int*   ei = (const int*)d_in[1];   // [2, E]: sources then targets
    const float* ew = (const float*)d_in[2];
    const float* W1 = (const float*)d_in[3];
    const float* b1 = (const float*)d_in[4];
    const float* W2 = (const float*)d_in[5];
    const float* b2 = (const float*)d_in[6];
    float* out = (float*)d_out;

    // workspace carve-up (256 B aligned). tmp buffers are dead after
    // fine_sort, so h overlays tmp_sw and a overlays tmp_t (stream-ordered).
    char* p = (char*)d_ws;
    auto carve = [&](size_t bytes) { char* r = p; p += (bytes + 255) & ~(size_t)255; return r; };
    float*   dis     = (float*)carve(N_NODES * 4);
    int*     rowptr  = (int*)carve((N_NODES + 1) * 4);
    int*     gcnt    = (int*)carve(256 * 4);
    int*     start   = (int*)carve(257 * 4);
    int*     gcursor = (int*)carve(256 * 4);
    EdgeRec* ed      = (EdgeRec*)carve((size_t)N_EDGES * 8);
    char*    r2      = carve((size_t)N_EDGES * 8);    // tmp_sw, then h
    char*    r3      = carve((size_t)N_NODES * 64 * 4); // tmp_t (first 12.8MB), then a
    EdgeRec* tmp_sw  = (EdgeRec*)r2;
    int*     tmp_t   = (int*)r3;
    float*   h       = (float*)r2;
    float*   a       = (float*)r3;

    const int TB = 256;
    // --- CSR build (bucketed, no large-scale random global atomics) ---
    hipMemsetAsync(gcnt, 0, 256 * sizeof(int), stream);
    coarse_hist<<<CH_GRID, 256, 0, stream>>>(ei + N_EDGES, gcnt);
    coarse_scan<<<1, 256, 0, stream>>>(gcnt, start, gcursor);
    scatter_coarse<<<SC_GRID, 256, 0, stream>>>(ei, ew, gcursor, tmp_sw, tmp_t);
    fine_sort<<<NBUCKET, 512, 0, stream>>>(start, tmp_sw, tmp_t, rowptr, dis, ed);
    fixup_kernel<<<(N_EDGES + TB - 1) / TB, TB, 0, stream>>>(ed, dis);

    // --- layer 1: h = x@W1 ; a = relu(agg(h) + b1) ---
    mm1_kernel<<<N_NODES / 16, TB, 0, stream>>>(x, W1, h);
    agg_kernel<<<N_NODES / 4, TB, 0, stream>>>(rowptr, ed, h, dis, b1, a, 1);

    // --- layer 2: h = a@W2 ; out = agg(h) + b2 ---
    mm2_kernel<<<N_NODES / 16, TB, 0, stream>>>(a, W2, h);
    agg_kernel<<<N_NODES / 4, TB, 0, stream>>>(rowptr, ed, h, dis, b2, out, 0);
}

// Round 4
// 595.965 us; speedup vs baseline: 3.0169x; 1.1157x over previous
//
#include <hip/hip_runtime.h>

#define N_NODES 100000
#define N_EDGES 3200000
#define IN_C 128
#define HID_C 64
#define OUT_C 64

#define NBUCKET 196          // ceil(N_NODES / 512); bucket = target >> 9
#define CH_GRID 1563         // ceil(E / 2048) for coarse hist (256 thr x 8 edges)
#define SC_GRID 782          // ceil(E / 4096) for coarse scatter (256 thr x 16 edges)

struct EdgeRec { int s; float v; };              // source node, w*dis[src]
struct Rec16   { int s; float v; int t; int z; };  // staged edge (one dwordx4)

// ---- coarse histogram: count edges per 512-node bucket -------------------
__global__ __launch_bounds__(256) void coarse_hist(const int* __restrict__ tgt,
                                                   int* __restrict__ gcnt) {
    __shared__ int hist[256];
    int tid = threadIdx.x;
    hist[tid] = 0;
    __syncthreads();
    int base = blockIdx.x * 2048;
    for (int i = 0; i < 8; ++i) {
        int e = base + i * 256 + tid;
        if (e < N_EDGES) atomicAdd(&hist[tgt[e] >> 9], 1);
    }
    __syncthreads();
    if (hist[tid]) atomicAdd(&gcnt[tid], hist[tid]);
}

// ---- exclusive scan of 256 bucket counts (single block) ------------------
__global__ __launch_bounds__(256) void coarse_scan(const int* __restrict__ gcnt,
                                                   int* __restrict__ start,
                                                   int* __restrict__ cursor) {
    __shared__ int s[256];
    int tid = threadIdx.x;
    int v = gcnt[tid];
    s[tid] = v;
    __syncthreads();
    for (int off = 1; off < 256; off <<= 1) {
        int t = s[tid];
        int add = (tid >= off) ? s[tid - off] : 0;
        __syncthreads();
        s[tid] = t + add;
        __syncthreads();
    }
    int excl = s[tid] - v;
    start[tid] = excl;
    cursor[tid] = excl;
    if (tid == 255) start[256] = s[255];   // == N_EDGES
}

// ---- coarse scatter: edges -> bucket-major order (block range reservation)
__global__ __launch_bounds__(256) void scatter_coarse(const int* __restrict__ ei,
                                                      const float* __restrict__ ew,
                                                      int* __restrict__ gcursor,
                                                      Rec16* __restrict__ tmp) {
    __shared__ int hist[256];
    __shared__ int blockBase[256];
    __shared__ int lcur[256];
    int tid = threadIdx.x;
    hist[tid] = 0;
    __syncthreads();
    int base = blockIdx.x * 4096;
    int ts[16];
    for (int i = 0; i < 16; ++i) {
        int e = base + i * 256 + tid;
        if (e < N_EDGES) {
            int t = ei[N_EDGES + e];
            ts[i] = t;
            atomicAdd(&hist[t >> 9], 1);
        } else ts[i] = -1;
    }
    __syncthreads();
    blockBase[tid] = atomicAdd(&gcursor[tid], hist[tid]);
    lcur[tid] = 0;
    __syncthreads();
    for (int i = 0; i < 16; ++i) {
        if (ts[i] >= 0) {
            int e = base + i * 256 + tid;
            int b = ts[i] >> 9;
            int off = atomicAdd(&lcur[b], 1);
            Rec16 r;
            r.s = ei[e];
            r.v = ew[e];
            r.t = ts[i];
            r.z = 0;
            tmp[blockBase[b] + off] = r;
        }
    }
}

// ---- per-bucket counting sort + rowptr + dis (one block per bucket) ------
__global__ __launch_bounds__(512) void fine_sort(const int* __restrict__ start,
                                                 const Rec16* __restrict__ tmp,
                                                 int* __restrict__ rowptr,
                                                 float* __restrict__ dis,
                                                 EdgeRec* __restrict__ ed) {
    __shared__ int   cnt[512];
    __shared__ float wdeg[512];
    __shared__ int   s[512];
    int tid = threadIdx.x;
    int nodeBase = blockIdx.x << 9;
    int bb = start[blockIdx.x];
    int be = start[blockIdx.x + 1];
    cnt[tid] = 0;
    wdeg[tid] = 0.f;
    __syncthreads();
    for (int e = bb + tid; e < be; e += 512) {
        Rec16 r = tmp[e];
        int l = r.t - nodeBase;
        atomicAdd(&cnt[l], 1);
        atomicAdd(&wdeg[l], r.v);
    }
    __syncthreads();
    int v = cnt[tid];
    s[tid] = v;
    __syncthreads();
    for (int off = 1; off < 512; off <<= 1) {
        int t = s[tid];
        int add = (tid >= off) ? s[tid - off] : 0;
        __syncthreads();
        s[tid] = t + add;
        __syncthreads();
    }
    int excl = s[tid] - v;
    int node = nodeBase + tid;
    if (node < N_NODES) {
        rowptr[node] = bb + excl;
        dis[node] = rsqrtf(wdeg[tid] + 1.0f);   // +1 = self-loop weight
    }
    if (node == N_NODES) rowptr[N_NODES] = N_EDGES;
    cnt[tid] = excl;       // reuse as cursor
    __syncthreads();
    for (int e = bb + tid; e < be; e += 512) {
        Rec16 r = tmp[e];
        int l = r.t - nodeBase;
        int p = atomicAdd(&cnt[l], 1);
        EdgeRec o;
        o.s = r.s;
        o.v = r.v;
        ed[bb + p] = o;
    }
}

// ---- fold dis[src] into edge values (2 edges per thread, dwordx4) --------
__global__ void fixup_kernel(EdgeRec* __restrict__ ed,
                             const float* __restrict__ dis) {
    int i = blockIdx.x * blockDim.x + threadIdx.x;
    int e = i * 2;
    if (e + 1 < N_EDGES) {
        EdgeRec r0 = ed[e], r1 = ed[e + 1];
        r0.v *= dis[r0.s];
        r1.v *= dis[r1.s];
        ed[e] = r0;
        ed[e + 1] = r1;
    } else if (e < N_EDGES) {
        EdgeRec r0 = ed[e];
        r0.v *= dis[r0.s];
        ed[e] = r0;
    }
}

// ---- h = x @ W1   [N,128] @ [128,64] ------------------------------------
__global__ __launch_bounds__(256) void mm1_kernel(const float* __restrict__ x,
                                                  const float* __restrict__ W,
                                                  float* __restrict__ h) {
    __shared__ float xs[16][IN_C];      // 8 KB
    __shared__ float wsm[IN_C][HID_C];  // 32 KB
    int tid = threadIdx.x;
    for (int i = tid; i < IN_C * HID_C; i += 256) wsm[i >> 6][i & 63] = W[i];
    int rowBase = blockIdx.x * 16;
    for (int i = tid; i < 16 * IN_C; i += 256) {
        int r = i >> 7, k = i & 127;
        xs[r][k] = x[(rowBase + r) * IN_C + k];
    }
    __syncthreads();
    int c = tid & 63, rg = tid >> 6;
    float a0 = 0.f, a1 = 0.f, a2 = 0.f, a3 = 0.f;
    for (int k = 0; k < IN_C; ++k) {
        float wv = wsm[k][c];
        a0 += xs[rg * 4 + 0][k] * wv;
        a1 += xs[rg * 4 + 1][k] * wv;
        a2 += xs[rg * 4 + 2][k] * wv;
        a3 += xs[rg * 4 + 3][k] * wv;
    }
    h[(rowBase + rg * 4 + 0) * HID_C + c] = a0;
    h[(rowBase + rg * 4 + 1) * HID_C + c] = a1;
    h[(rowBase + rg * 4 + 2) * HID_C + c] = a2;
    h[(rowBase + rg * 4 + 3) * HID_C + c] = a3;
}

// ---- h2 = a @ W2   [N,64] @ [64,64] -------------------------------------
__global__ __launch_bounds__(256) void mm2_kernel(const float* __restrict__ a,
                                                  const float* __restrict__ W,
                                                  float* __restrict__ h) {
    __shared__ float as[16][HID_C];      // 4 KB
    __shared__ float wsm[HID_C][OUT_C];  // 16 KB
    int tid = threadIdx.x;
    for (int i = tid; i < HID_C * OUT_C; i += 256) wsm[i >> 6][i & 63] = W[i];
    int rowBase = blockIdx.x * 16;
    for (int i = tid; i < 16 * HID_C; i += 256) {
        int r = i >> 6, k = i & 63;
        as[r][k] = a[(rowBase + r) * HID_C + k];
    }
    __syncthreads();
    int c = tid & 63, rg = tid >> 6;
    float a0 = 0.f, a1 = 0.f, a2 = 0.f, a3 = 0.f;
    for (int k = 0; k < HID_C; ++k) {
        float wv = wsm[k][c];
        a0 += as[rg * 4 + 0][k] * wv;
        a1 += as[rg * 4 + 1][k] * wv;
        a2 += as[rg * 4 + 2][k] * wv;
        a3 += as[rg * 4 + 3][k] * wv;
    }
    h[(rowBase + rg * 4 + 0) * OUT_C + c] = a0;
    h[(rowBase + rg * 4 + 1) * OUT_C + c] = a1;
    h[(rowBase + rg * 4 + 2) * OUT_C + c] = a2;
    h[(rowBase + rg * 4 + 3) * OUT_C + c] = a3;
}

// ---- CSR aggregate + fused epilogue --------------------------------------
// one wave per node; 4 groups of 16 lanes, one edge per group per step,
// lane reads float4 of the h row (16 x 16B = 256B). Cross-group shuffle
// reduction at the end. No atomics.
__global__ __launch_bounds__(256) void agg_kernel(const int* __restrict__ rowptr,
                                                  const EdgeRec* __restrict__ ed,
                                                  const float* __restrict__ h,
                                                  const float* __restrict__ dis,
                                                  const float* __restrict__ b,
                                                  float* __restrict__ out,
                                                  int relu) {
    int node = blockIdx.x * 4 + (threadIdx.x >> 6);
    int lane = threadIdx.x & 63;
    int g = lane >> 4;        // edge group 0..3
    int cl = lane & 15;       // channel quad: channels 4*cl .. 4*cl+3
    int beg = rowptr[node];
    int end = rowptr[node + 1];
    const float4* h4 = (const float4*)h;
    float4 acc = make_float4(0.f, 0.f, 0.f, 0.f);
    int e = beg + g;
    // unrolled x2: 8 edges in flight per wave
    for (; e + 4 < end; e += 8) {
        EdgeRec r0 = ed[e];
        EdgeRec r1 = ed[e + 4];
        float4 h0 = h4[r0.s * 16 + cl];
        float4 h1 = h4[r1.s * 16 + cl];
        acc.x += r0.v * h0.x; acc.y += r0.v * h0.y;
        acc.z += r0.v * h0.z; acc.w += r0.v * h0.w;
        acc.x += r1.v * h1.x; acc.y += r1.v * h1.y;
        acc.z += r1.v * h1.z; acc.w += r1.v * h1.w;
    }
    if (e < end) {
        EdgeRec r0 = ed[e];
        float4 h0 = h4[r0.s * 16 + cl];
        acc.x += r0.v * h0.x; acc.y += r0.v * h0.y;
        acc.z += r0.v * h0.z; acc.w += r0.v * h0.w;
    }
    // reduce across the 4 groups (lanes cl, cl+16, cl+32, cl+48)
    acc.x += __shfl_xor(acc.x, 16, 64);
    acc.y += __shfl_xor(acc.y, 16, 64);
    acc.z += __shfl_xor(acc.z, 16, 64);
    acc.w += __shfl_xor(acc.w, 16, 64);
    acc.x += __shfl_xor(acc.x, 32, 64);
    acc.y += __shfl_xor(acc.y, 32, 64);
    acc.z += __shfl_xor(acc.z, 32, 64);
    acc.w += __shfl_xor(acc.w, 32, 64);
    if (g == 0) {
        float d = dis[node];
        float4 hs = h4[node * 16 + cl];
        float4 bv = ((const float4*)b)[cl];
        float4 v;
        v.x = d * acc.x + d * d * hs.x + bv.x;
        v.y = d * acc.y + d * d * hs.y + bv.y;
        v.z = d * acc.z + d * d * hs.z + bv.z;
        v.w = d * acc.w + d * d * hs.w + bv.w;
        if (relu) {
            v.x = fmaxf(v.x, 0.f); v.y = fmaxf(v.y, 0.f);
            v.z = fmaxf(v.z, 0.f); v.w = fmaxf(v.w, 0.f);
        }
        ((float4*)out)[node * 16 + cl] = v;
    }
}

extern "C" void kernel_launch(void* const* d_in, const int* in_sizes, int n_in,
                              void* d_out, int out_size, void* d_ws, size_t ws_size,
                              hipStream_t stream) {
    const float* x  = (const float*)d_in[0];
    const int*   ei = (const int*)d_in[1];   // [2, E]: sources then targets
    const float* ew = (const float*)d_in[2];
    const float* W1 = (const float*)d_in[3];
    const float* b1 = (const float*)d_in[4];
    const float* W2 = (const float*)d_in[5];
    const float* b2 = (const float*)d_in[6];
    float* out = (float*)d_out;

    // workspace carve-up (256 B aligned). tmp (51.2 MB) is dead after
    // fine_sort; h and a overlay it (stream-ordered reuse).
    char* p = (char*)d_ws;
    auto carve = [&](size_t bytes) { char* r = p; p += (bytes + 255) & ~(size_t)255; return r; };
    float*   dis     = (float*)carve(N_NODES * 4);
    int*     rowptr  = (int*)carve((N_NODES + 1) * 4);
    int*     gcnt    = (int*)carve(256 * 4);
    int*     start   = (int*)carve(257 * 4);
    int*     gcursor = (int*)carve(256 * 4);
    EdgeRec* ed      = (EdgeRec*)carve((size_t)N_EDGES * 8);
    char*    r2      = carve((size_t)N_EDGES * 16);   // tmp, then h + a
    Rec16*   tmp     = (Rec16*)r2;
    float*   h       = (float*)r2;
    float*   a       = (float*)(r2 + (size_t)N_NODES * 64 * 4);

    const int TB = 256;
    // --- CSR build (bucketed, no large-scale random global atomics) ---
    hipMemsetAsync(gcnt, 0, 256 * sizeof(int), stream);
    coarse_hist<<<CH_GRID, 256, 0, stream>>>(ei + N_EDGES, gcnt);
    coarse_scan<<<1, 256, 0, stream>>>(gcnt, start, gcursor);
    scatter_coarse<<<SC_GRID, 256, 0, stream>>>(ei, ew, gcursor, tmp);
    fine_sort<<<NBUCKET, 512, 0, stream>>>(start, tmp, rowptr, dis, ed);
    fixup_kernel<<<(N_EDGES / 2 + TB - 1) / TB, TB, 0, stream>>>(ed, dis);

    // --- layer 1: h = x@W1 ; a = relu(agg(h) + b1) ---
    mm1_kernel<<<N_NODES / 16, TB, 0, stream>>>(x, W1, h);
    agg_kernel<<<N_NODES / 4, TB, 0, stream>>>(rowptr, ed, h, dis, b1, a, 1);

    // --- layer 2: h = a@W2 ; out = agg(h) + b2 ---
    mm2_kernel<<<N_NODES / 16, TB, 0, stream>>>(a, W2, h);
    agg_kernel<<<N_NODES / 4, TB, 0, stream>>>(rowptr, ed, h, dis, b2, out, 0);
}

// Round 5
// 497.174 us; speedup vs baseline: 3.6164x; 1.1987x over previous
//
#include <hip/hip_runtime.h>
#include <hip/hip_bf16.h>

#define N_NODES 100000
#define N_EDGES 3200000
#define IN_C 128
#define HID_C 64
#define OUT_C 64

#define NBUCKET 196          // ceil(N_NODES / 512); bucket = target >> 9
#define CH_GRID 1563         // ceil(E / 2048) for coarse hist (256 thr x 8 edges)
#define SC_GRID 782          // ceil(E / 4096) for coarse scatter (256 thr x 16 edges)

struct EdgeRec { int s; float v; };                // source node, w*dis[src]
struct Rec16   { int s; float v; int t; int z; };  // staged edge (one dwordx4)

__device__ __forceinline__ unsigned pack_bf16(float lo, float hi) {
    unsigned short l = __hip_bfloat16_raw(__float2bfloat16(lo)).x;
    unsigned short h = __hip_bfloat16_raw(__float2bfloat16(hi)).x;
    return ((unsigned)h << 16) | l;
}
__device__ __forceinline__ float bf_lo(unsigned u) {
    union { unsigned u; float f; } c; c.u = u << 16; return c.f;
}
__device__ __forceinline__ float bf_hi(unsigned u) {
    union { unsigned u; float f; } c; c.u = u & 0xffff0000u; return c.f;
}

// ---- coarse histogram: count edges per 512-node bucket -------------------
__global__ __launch_bounds__(256) void coarse_hist(const int* __restrict__ tgt,
                                                   int* __restrict__ gcnt) {
    __shared__ int hist[256];
    int tid = threadIdx.x;
    hist[tid] = 0;
    __syncthreads();
    int base = blockIdx.x * 2048;
    for (int i = 0; i < 8; ++i) {
        int e = base + i * 256 + tid;
        if (e < N_EDGES) atomicAdd(&hist[tgt[e] >> 9], 1);
    }
    __syncthreads();
    if (hist[tid]) atomicAdd(&gcnt[tid], hist[tid]);
}

// ---- exclusive scan of 256 bucket counts (single block) ------------------
__global__ __launch_bounds__(256) void coarse_scan(const int* __restrict__ gcnt,
                                                   int* __restrict__ start,
                                                   int* __restrict__ cursor) {
    __shared__ int s[256];
    int tid = threadIdx.x;
    int v = gcnt[tid];
    s[tid] = v;
    __syncthreads();
    for (int off = 1; off < 256; off <<= 1) {
        int t = s[tid];
        int add = (tid >= off) ? s[tid - off] : 0;
        __syncthreads();
        s[tid] = t + add;
        __syncthreads();
    }
    int excl = s[tid] - v;
    start[tid] = excl;
    cursor[tid] = excl;
    if (tid == 255) start[256] = s[255];   // == N_EDGES
}

// ---- coarse scatter: edges -> bucket-major order (block range reservation)
__global__ __launch_bounds__(256) void scatter_coarse(const int* __restrict__ ei,
                                                      const float* __restrict__ ew,
                                                      int* __restrict__ gcursor,
                                                      Rec16* __restrict__ tmp) {
    __shared__ int hist[256];
    __shared__ int blockBase[256];
    __shared__ int lcur[256];
    int tid = threadIdx.x;
    hist[tid] = 0;
    __syncthreads();
    int base = blockIdx.x * 4096;
    int ts[16];
    for (int i = 0; i < 16; ++i) {
        int e = base + i * 256 + tid;
        if (e < N_EDGES) {
            int t = ei[N_EDGES + e];
            ts[i] = t;
            atomicAdd(&hist[t >> 9], 1);
        } else ts[i] = -1;
    }
    __syncthreads();
    blockBase[tid] = atomicAdd(&gcursor[tid], hist[tid]);
    lcur[tid] = 0;
    __syncthreads();
    for (int i = 0; i < 16; ++i) {
        if (ts[i] >= 0) {
            int e = base + i * 256 + tid;
            int b = ts[i] >> 9;
            int off = atomicAdd(&lcur[b], 1);
            Rec16 r;
            r.s = ei[e];
            r.v = ew[e];
            r.t = ts[i];
            r.z = 0;
            tmp[blockBase[b] + off] = r;
        }
    }
}

// ---- per-bucket counting sort + rowptr + dis (one block per bucket) ------
__global__ __launch_bounds__(512) void fine_sort(const int* __restrict__ start,
                                                 const Rec16* __restrict__ tmp,
                                                 int* __restrict__ rowptr,
                                                 float* __restrict__ dis,
                                                 EdgeRec* __restrict__ ed) {
    __shared__ int   cnt[512];
    __shared__ float wdeg[512];
    __shared__ int   s[512];
    int tid = threadIdx.x;
    int nodeBase = blockIdx.x << 9;
    int bb = start[blockIdx.x];
    int be = start[blockIdx.x + 1];
    cnt[tid] = 0;
    wdeg[tid] = 0.f;
    __syncthreads();
    for (int e = bb + tid; e < be; e += 512) {
        Rec16 r = tmp[e];
        int l = r.t - nodeBase;
        atomicAdd(&cnt[l], 1);
        atomicAdd(&wdeg[l], r.v);
    }
    __syncthreads();
    int v = cnt[tid];
    s[tid] = v;
    __syncthreads();
    for (int off = 1; off < 512; off <<= 1) {
        int t = s[tid];
        int add = (tid >= off) ? s[tid - off] : 0;
        __syncthreads();
        s[tid] = t + add;
        __syncthreads();
    }
    int excl = s[tid] - v;
    int node = nodeBase + tid;
    if (node < N_NODES) {
        rowptr[node] = bb + excl;
        dis[node] = rsqrtf(wdeg[tid] + 1.0f);   // +1 = self-loop weight
    }
    if (node == N_NODES) rowptr[N_NODES] = N_EDGES;
    cnt[tid] = excl;       // reuse as cursor
    __syncthreads();
    for (int e = bb + tid; e < be; e += 512) {
        Rec16 r = tmp[e];
        int l = r.t - nodeBase;
        int p = atomicAdd(&cnt[l], 1);
        EdgeRec o;
        o.s = r.s;
        o.v = r.v;
        ed[bb + p] = o;
    }
}

// ---- fold dis[src] into edge values (2 edges per thread, dwordx4) --------
__global__ void fixup_kernel(EdgeRec* __restrict__ ed,
                             const float* __restrict__ dis) {
    int i = blockIdx.x * blockDim.x + threadIdx.x;
    int e = i * 2;
    if (e + 1 < N_EDGES) {
        EdgeRec r0 = ed[e], r1 = ed[e + 1];
        r0.v *= dis[r0.s];
        r1.v *= dis[r1.s];
        ed[e] = r0;
        ed[e + 1] = r1;
    } else if (e < N_EDGES) {
        EdgeRec r0 = ed[e];
        r0.v *= dis[r0.s];
        ed[e] = r0;
    }
}

// ---- h = x @ W1   [N,128] @ [128,64], output packed bf16 -----------------
__global__ __launch_bounds__(256) void mm1_kernel(const float* __restrict__ x,
                                                  const float* __restrict__ W,
                                                  unsigned* __restrict__ h) {
    __shared__ float xs[16][IN_C];      // 8 KB
    __shared__ float wsm[IN_C][HID_C];  // 32 KB
    int tid = threadIdx.x;
    for (int i = tid; i < IN_C * HID_C; i += 256) wsm[i >> 6][i & 63] = W[i];
    int rowBase = blockIdx.x * 16;
    for (int i = tid; i < 16 * IN_C; i += 256) {
        int r = i >> 7, k = i & 127;
        xs[r][k] = x[(rowBase + r) * IN_C + k];
    }
    __syncthreads();
    int c = tid & 63, rg = tid >> 6;
    float a0 = 0.f, a1 = 0.f, a2 = 0.f, a3 = 0.f;
    for (int k = 0; k < IN_C; ++k) {
        float wv = wsm[k][c];
        a0 += xs[rg * 4 + 0][k] * wv;
        a1 += xs[rg * 4 + 1][k] * wv;
        a2 += xs[rg * 4 + 2][k] * wv;
        a3 += xs[rg * 4 + 3][k] * wv;
    }
    // pack channel pairs (c even holds c, c+1) -> coalesced 4B stores
    float o0 = __shfl_xor(a0, 1, 64);
    float o1 = __shfl_xor(a1, 1, 64);
    float o2 = __shfl_xor(a2, 1, 64);
    float o3 = __shfl_xor(a3, 1, 64);
    if ((c & 1) == 0) {
        int ci = c >> 1;
        h[(rowBase + rg * 4 + 0) * 32 + ci] = pack_bf16(a0, o0);
        h[(rowBase + rg * 4 + 1) * 32 + ci] = pack_bf16(a1, o1);
        h[(rowBase + rg * 4 + 2) * 32 + ci] = pack_bf16(a2, o2);
        h[(rowBase + rg * 4 + 3) * 32 + ci] = pack_bf16(a3, o3);
    }
}

// ---- h2 = a @ W2   [N,64] @ [64,64], output packed bf16 ------------------
__global__ __launch_bounds__(256) void mm2_kernel(const float* __restrict__ a,
                                                  const float* __restrict__ W,
                                                  unsigned* __restrict__ h) {
    __shared__ float as[16][HID_C];      // 4 KB
    __shared__ float wsm[HID_C][OUT_C];  // 16 KB
    int tid = threadIdx.x;
    for (int i = tid; i < HID_C * OUT_C; i += 256) wsm[i >> 6][i & 63] = W[i];
    int rowBase = blockIdx.x * 16;
    for (int i = tid; i < 16 * HID_C; i += 256) {
        int r = i >> 6, k = i & 63;
        as[r][k] = a[(rowBase + r) * HID_C + k];
    }
    __syncthreads();
    int c = tid & 63, rg = tid >> 6;
    float a0 = 0.f, a1 = 0.f, a2 = 0.f, a3 = 0.f;
    for (int k = 0; k < HID_C; ++k) {
        float wv = wsm[k][c];
        a0 += as[rg * 4 + 0][k] * wv;
        a1 += as[rg * 4 + 1][k] * wv;
        a2 += as[rg * 4 + 2][k] * wv;
        a3 += as[rg * 4 + 3][k] * wv;
    }
    float o0 = __shfl_xor(a0, 1, 64);
    float o1 = __shfl_xor(a1, 1, 64);
    float o2 = __shfl_xor(a2, 1, 64);
    float o3 = __shfl_xor(a3, 1, 64);
    if ((c & 1) == 0) {
        int ci = c >> 1;
        h[(rowBase + rg * 4 + 0) * 32 + ci] = pack_bf16(a0, o0);
        h[(rowBase + rg * 4 + 1) * 32 + ci] = pack_bf16(a1, o1);
        h[(rowBase + rg * 4 + 2) * 32 + ci] = pack_bf16(a2, o2);
        h[(rowBase + rg * 4 + 3) * 32 + ci] = pack_bf16(a3, o3);
    }
}

// ---- CSR aggregate + fused epilogue (bf16 h rows, 128 B) ------------------
// one wave per node; 8 groups of 8 lanes, one edge per group per step,
// lane reads uint4 = 8 bf16 channels. 16 edges in flight (unroll x2).
__global__ __launch_bounds__(256) void agg_kernel(const int* __restrict__ rowptr,
                                                  const EdgeRec* __restrict__ ed,
                                                  const unsigned* __restrict__ h,
                                                  const float* __restrict__ dis,
                                                  const float* __restrict__ b,
                                                  float* __restrict__ out,
                                                  int relu) {
    int node = blockIdx.x * 4 + (threadIdx.x >> 6);
    int lane = threadIdx.x & 63;
    int g = lane >> 3;        // edge group 0..7
    int cl = lane & 7;        // channel octet: channels 8*cl .. 8*cl+7
    int beg = rowptr[node];
    int end = rowptr[node + 1];
    const uint4* h16 = (const uint4*)h;   // 8 uint4 per 64-ch row
    float acc[8] = {0.f, 0.f, 0.f, 0.f, 0.f, 0.f, 0.f, 0.f};
    int e = beg + g;
    for (; e + 8 < end; e += 16) {
        EdgeRec r0 = ed[e];
        EdgeRec r1 = ed[e + 8];
        uint4 u0 = h16[r0.s * 8 + cl];
        uint4 u1 = h16[r1.s * 8 + cl];
        acc[0] += r0.v * bf_lo(u0.x); acc[1] += r0.v * bf_hi(u0.x);
        acc[2] += r0.v * bf_lo(u0.y); acc[3] += r0.v * bf_hi(u0.y);
        acc[4] += r0.v * bf_lo(u0.z); acc[5] += r0.v * bf_hi(u0.z);
        acc[6] += r0.v * bf_lo(u0.w); acc[7] += r0.v * bf_hi(u0.w);
        acc[0] += r1.v * bf_lo(u1.x); acc[1] += r1.v * bf_hi(u1.x);
        acc[2] += r1.v * bf_lo(u1.y); acc[3] += r1.v * bf_hi(u1.y);
        acc[4] += r1.v * bf_lo(u1.z); acc[5] += r1.v * bf_hi(u1.z);
        acc[6] += r1.v * bf_lo(u1.w); acc[7] += r1.v * bf_hi(u1.w);
    }
    if (e < end) {
        EdgeRec r0 = ed[e];
        uint4 u0 = h16[r0.s * 8 + cl];
        acc[0] += r0.v * bf_lo(u0.x); acc[1] += r0.v * bf_hi(u0.x);
        acc[2] += r0.v * bf_lo(u0.y); acc[3] += r0.v * bf_hi(u0.y);
        acc[4] += r0.v * bf_lo(u0.z); acc[5] += r0.v * bf_hi(u0.z);
        acc[6] += r0.v * bf_lo(u0.w); acc[7] += r0.v * bf_hi(u0.w);
    }
    // reduce across the 8 groups (same cl)
    #pragma unroll
    for (int k = 0; k < 8; ++k) {
        acc[k] += __shfl_xor(acc[k], 8, 64);
        acc[k] += __shfl_xor(acc[k], 16, 64);
        acc[k] += __shfl_xor(acc[k], 32, 64);
    }
    if (g == 0) {
        float d = dis[node];
        uint4 us = h16[node * 8 + cl];
        float hs[8] = { bf_lo(us.x), bf_hi(us.x), bf_lo(us.y), bf_hi(us.y),
                        bf_lo(us.z), bf_hi(us.z), bf_lo(us.w), bf_hi(us.w) };
        const float4* b4 = (const float4*)b;
        float4 bv0 = b4[cl * 2], bv1 = b4[cl * 2 + 1];
        float4 v0, v1;
        v0.x = d * acc[0] + d * d * hs[0] + bv0.x;
        v0.y = d * acc[1] + d * d * hs[1] + bv0.y;
        v0.z = d * acc[2] + d * d * hs[2] + bv0.z;
        v0.w = d * acc[3] + d * d * hs[3] + bv0.w;
        v1.x = d * acc[4] + d * d * hs[4] + bv1.x;
        v1.y = d * acc[5] + d * d * hs[5] + bv1.y;
        v1.z = d * acc[6] + d * d * hs[6] + bv1.z;
        v1.w = d * acc[7] + d * d * hs[7] + bv1.w;
        if (relu) {
            v0.x = fmaxf(v0.x, 0.f); v0.y = fmaxf(v0.y, 0.f);
            v0.z = fmaxf(v0.z, 0.f); v0.w = fmaxf(v0.w, 0.f);
            v1.x = fmaxf(v1.x, 0.f); v1.y = fmaxf(v1.y, 0.f);
            v1.z = fmaxf(v1.z, 0.f); v1.w = fmaxf(v1.w, 0.f);
        }
        float4* o4 = (float4*)out;
        o4[node * 16 + cl * 2]     = v0;
        o4[node * 16 + cl * 2 + 1] = v1;
    }
}

extern "C" void kernel_launch(void* const* d_in, const int* in_sizes, int n_in,
                              void* d_out, int out_size, void* d_ws, size_t ws_size,
                              hipStream_t stream) {
    const float* x  = (const float*)d_in[0];
    const int*   ei = (const int*)d_in[1];   // [2, E]: sources then targets
    const float* ew = (const float*)d_in[2];
    const float* W1 = (const float*)d_in[3];
    const float* b1 = (const float*)d_in[4];
    const float* W2 = (const float*)d_in[5];
    const float* b2 = (const float*)d_in[6];
    float* out = (float*)d_out;

    // workspace carve-up (256 B aligned). tmp (51.2 MB) is dead after
    // fine_sort; bf16 h (12.8 MB, reused across layers) + f32 a (25.6 MB)
    // overlay it (stream-ordered reuse).
    char* p = (char*)d_ws;
    auto carve = [&](size_t bytes) { char* r = p; p += (bytes + 255) & ~(size_t)255; return r; };
    float*    dis     = (float*)carve(N_NODES * 4);
    int*      rowptr  = (int*)carve((N_NODES + 1) * 4);
    int*      gcnt    = (int*)carve(256 * 4);
    int*      start   = (int*)carve(257 * 4);
    int*      gcursor = (int*)carve(256 * 4);
    EdgeRec*  ed      = (EdgeRec*)carve((size_t)N_EDGES * 8);
    char*     r2      = carve((size_t)N_EDGES * 16);   // tmp, then h + a
    Rec16*    tmp     = (Rec16*)r2;
    unsigned* h       = (unsigned*)r2;                         // N*64 bf16 = 12.8 MB
    float*    a       = (float*)(r2 + (size_t)N_NODES * 64 * 2); // N*64 f32 = 25.6 MB

    const int TB = 256;
    // --- CSR build (bucketed, no large-scale random global atomics) ---
    hipMemsetAsync(gcnt, 0, 256 * sizeof(int), stream);
    coarse_hist<<<CH_GRID, 256, 0, stream>>>(ei + N_EDGES, gcnt);
    coarse_scan<<<1, 256, 0, stream>>>(gcnt, start, gcursor);
    scatter_coarse<<<SC_GRID, 256, 0, stream>>>(ei, ew, gcursor, tmp);
    fine_sort<<<NBUCKET, 512, 0, stream>>>(start, tmp, rowptr, dis, ed);
    fixup_kernel<<<(N_EDGES / 2 + TB - 1) / TB, TB, 0, stream>>>(ed, dis);

    // --- layer 1: h = bf16(x@W1) ; a = relu(agg(h) + b1) ---
    mm1_kernel<<<N_NODES / 16, TB, 0, stream>>>(x, W1, h);
    agg_kernel<<<N_NODES / 4, TB, 0, stream>>>(rowptr, ed, h, dis, b1, a, 1);

    // --- layer 2: h = bf16(a@W2) ; out = agg(h) + b2 ---
    mm2_kernel<<<N_NODES / 16, TB, 0, stream>>>(a, W2, h);
    agg_kernel<<<N_NODES / 4, TB, 0, stream>>>(rowptr, ed, h, dis, b2, out, 0);
}

// Round 6
// 477.895 us; speedup vs baseline: 3.7622x; 1.0403x over previous
//
#include <hip/hip_runtime.h>
#include <hip/hip_bf16.h>

#define N_NODES 100000
#define N_EDGES 3200000
#define IN_C 128
#define HID_C 64
#define OUT_C 64

#define NBUCKET 196          // ceil(N_NODES / 512); bucket = target >> 9
#define CH_GRID 1563         // ceil(E / 2048) for coarse hist (256 thr x 8 edges)
#define SC_EDGES 16384       // edges per scatter block
#define SC_GRID 196          // ceil(E / SC_EDGES)

struct EdgeRec { int s; float v; };   // source node, raw edge weight w

// staged record: 8 B. x = f32 bits of w; y = s (17 bits) | t_local<<17 (9 bits)
__device__ __forceinline__ unsigned pack_bf16(float lo, float hi) {
    unsigned short l = __hip_bfloat16_raw(__float2bfloat16(lo)).x;
    unsigned short h = __hip_bfloat16_raw(__float2bfloat16(hi)).x;
    return ((unsigned)h << 16) | l;
}
__device__ __forceinline__ float bf_lo(unsigned u) {
    union { unsigned u; float f; } c; c.u = u << 16; return c.f;
}
__device__ __forceinline__ float bf_hi(unsigned u) {
    union { unsigned u; float f; } c; c.u = u & 0xffff0000u; return c.f;
}

// ---- coarse histogram: count edges per 512-node bucket -------------------
__global__ __launch_bounds__(256) void coarse_hist(const int* __restrict__ tgt,
                                                   int* __restrict__ gcnt) {
    __shared__ int hist[256];
    int tid = threadIdx.x;
    hist[tid] = 0;
    __syncthreads();
    int base = blockIdx.x * 2048;
    for (int i = 0; i < 8; ++i) {
        int e = base + i * 256 + tid;
        if (e < N_EDGES) atomicAdd(&hist[tgt[e] >> 9], 1);
    }
    __syncthreads();
    if (hist[tid]) atomicAdd(&gcnt[tid], hist[tid]);
}

// ---- exclusive scan of 256 bucket counts (single block) ------------------
__global__ __launch_bounds__(256) void coarse_scan(const int* __restrict__ gcnt,
                                                   int* __restrict__ start,
                                                   int* __restrict__ cursor) {
    __shared__ int s[256];
    int tid = threadIdx.x;
    int v = gcnt[tid];
    s[tid] = v;
    __syncthreads();
    for (int off = 1; off < 256; off <<= 1) {
        int t = s[tid];
        int add = (tid >= off) ? s[tid - off] : 0;
        __syncthreads();
        s[tid] = t + add;
        __syncthreads();
    }
    int excl = s[tid] - v;
    start[tid] = excl;
    cursor[tid] = excl;
    if (tid == 255) start[256] = s[255];   // == N_EDGES
}

// ---- coarse scatter: edges -> bucket-major order, 8-B packed records -----
// 16384 edges/block, two passes over the (LLC-warm) target array.
__global__ __launch_bounds__(256) void scatter_coarse(const int* __restrict__ ei,
                                                      const float* __restrict__ ew,
                                                      int* __restrict__ gcursor,
                                                      uint2* __restrict__ tmp) {
    __shared__ int hist[256];
    __shared__ int cur[256];
    int tid = threadIdx.x;
    hist[tid] = 0;
    __syncthreads();
    int base = blockIdx.x * SC_EDGES;
    int lim = base + SC_EDGES;
    if (lim > N_EDGES) lim = N_EDGES;
    for (int e = base + tid; e < lim; e += 256)
        atomicAdd(&hist[ei[N_EDGES + e] >> 9], 1);
    __syncthreads();
    cur[tid] = atomicAdd(&gcursor[tid], hist[tid]);
    __syncthreads();
    for (int e = base + tid; e < lim; e += 256) {
        int t = ei[N_EDGES + e];
        int b = t >> 9;
        int pos = atomicAdd(&cur[b], 1);
        uint2 r;
        r.x = __float_as_uint(ew[e]);
        r.y = (unsigned)ei[e] | ((unsigned)(t & 511) << 17);
        tmp[pos] = r;
    }
}

// ---- per-bucket counting sort + rowptr + dis (one block per bucket) ------
__global__ __launch_bounds__(512) void fine_sort(const int* __restrict__ start,
                                                 const uint2* __restrict__ tmp,
                                                 int* __restrict__ rowptr,
                                                 float* __restrict__ dis,
                                                 EdgeRec* __restrict__ ed) {
    __shared__ int   cnt[512];
    __shared__ float wdeg[512];
    __shared__ int   s[512];
    int tid = threadIdx.x;
    int nodeBase = blockIdx.x << 9;
    int bb = start[blockIdx.x];
    int be = start[blockIdx.x + 1];
    cnt[tid] = 0;
    wdeg[tid] = 0.f;
    __syncthreads();
    for (int e = bb + tid; e < be; e += 512) {
        uint2 r = tmp[e];
        int l = (r.y >> 17) & 511;
        atomicAdd(&cnt[l], 1);
        atomicAdd(&wdeg[l], __uint_as_float(r.x));
    }
    __syncthreads();
    int v = cnt[tid];
    s[tid] = v;
    __syncthreads();
    for (int off = 1; off < 512; off <<= 1) {
        int t = s[tid];
        int add = (tid >= off) ? s[tid - off] : 0;
        __syncthreads();
        s[tid] = t + add;
        __syncthreads();
    }
    int excl = s[tid] - v;
    int node = nodeBase + tid;
    if (node < N_NODES) {
        rowptr[node] = bb + excl;
        dis[node] = rsqrtf(wdeg[tid] + 1.0f);   // +1 = self-loop weight
    }
    if (node == N_NODES) rowptr[N_NODES] = N_EDGES;
    cnt[tid] = excl;       // reuse as cursor
    __syncthreads();
    for (int e = bb + tid; e < be; e += 512) {
        uint2 r = tmp[e];
        int l = (r.y >> 17) & 511;
        int p = atomicAdd(&cnt[l], 1);
        EdgeRec o;
        o.s = (int)(r.y & 0x1FFFFu);
        o.v = __uint_as_float(r.x);
        ed[bb + p] = o;
    }
}

// ---- h = bf16( dis[row] * (x @ W1) )   [N,128] @ [128,64] ----------------
// dis-scaling folded here removes the fixup pass: GCN update becomes
// out[t] = dis_t * (sum_e w_e * h'[s_e] + h'[t]) + b, with h' = dis.h.
__global__ __launch_bounds__(256) void mm1_kernel(const float* __restrict__ x,
                                                  const float* __restrict__ W,
                                                  const float* __restrict__ dis,
                                                  unsigned* __restrict__ h) {
    __shared__ float xs[16][IN_C];      // 8 KB
    __shared__ float wsm[IN_C][HID_C];  // 32 KB
    int tid = threadIdx.x;
    for (int i = tid; i < IN_C * HID_C; i += 256) wsm[i >> 6][i & 63] = W[i];
    int rowBase = blockIdx.x * 16;
    for (int i = tid; i < 16 * IN_C; i += 256) {
        int r = i >> 7, k = i & 127;
        xs[r][k] = x[(rowBase + r) * IN_C + k];
    }
    __syncthreads();
    int c = tid & 63, rg = tid >> 6;
    float a0 = 0.f, a1 = 0.f, a2 = 0.f, a3 = 0.f;
    for (int k = 0; k < IN_C; ++k) {
        float wv = wsm[k][c];
        a0 += xs[rg * 4 + 0][k] * wv;
        a1 += xs[rg * 4 + 1][k] * wv;
        a2 += xs[rg * 4 + 2][k] * wv;
        a3 += xs[rg * 4 + 3][k] * wv;
    }
    a0 *= dis[rowBase + rg * 4 + 0];
    a1 *= dis[rowBase + rg * 4 + 1];
    a2 *= dis[rowBase + rg * 4 + 2];
    a3 *= dis[rowBase + rg * 4 + 3];
    float o0 = __shfl_xor(a0, 1, 64);
    float o1 = __shfl_xor(a1, 1, 64);
    float o2 = __shfl_xor(a2, 1, 64);
    float o3 = __shfl_xor(a3, 1, 64);
    if ((c & 1) == 0) {
        int ci = c >> 1;
        h[(rowBase + rg * 4 + 0) * 32 + ci] = pack_bf16(a0, o0);
        h[(rowBase + rg * 4 + 1) * 32 + ci] = pack_bf16(a1, o1);
        h[(rowBase + rg * 4 + 2) * 32 + ci] = pack_bf16(a2, o2);
        h[(rowBase + rg * 4 + 3) * 32 + ci] = pack_bf16(a3, o3);
    }
}

// ---- h = bf16( dis[row] * (a @ W2) )   [N,64] @ [64,64] ------------------
__global__ __launch_bounds__(256) void mm2_kernel(const float* __restrict__ a,
                                                  const float* __restrict__ W,
                                                  const float* __restrict__ dis,
                                                  unsigned* __restrict__ h) {
    __shared__ float as[16][HID_C];      // 4 KB
    __shared__ float wsm[HID_C][OUT_C];  // 16 KB
    int tid = threadIdx.x;
    for (int i = tid; i < HID_C * OUT_C; i += 256) wsm[i >> 6][i & 63] = W[i];
    int rowBase = blockIdx.x * 16;
    for (int i = tid; i < 16 * HID_C; i += 256) {
        int r = i >> 6, k = i & 63;
        as[r][k] = a[(rowBase + r) * HID_C + k];
    }
    __syncthreads();
    int c = tid & 63, rg = tid >> 6;
    float a0 = 0.f, a1 = 0.f, a2 = 0.f, a3 = 0.f;
    for (int k = 0; k < HID_C; ++k) {
        float wv = wsm[k][c];
        a0 += as[rg * 4 + 0][k] * wv;
        a1 += as[rg * 4 + 1][k] * wv;
        a2 += as[rg * 4 + 2][k] * wv;
        a3 += as[rg * 4 + 3][k] * wv;
    }
    a0 *= dis[rowBase + rg * 4 + 0];
    a1 *= dis[rowBase + rg * 4 + 1];
    a2 *= dis[rowBase + rg * 4 + 2];
    a3 *= dis[rowBase + rg * 4 + 3];
    float o0 = __shfl_xor(a0, 1, 64);
    float o1 = __shfl_xor(a1, 1, 64);
    float o2 = __shfl_xor(a2, 1, 64);
    float o3 = __shfl_xor(a3, 1, 64);
    if ((c & 1) == 0) {
        int ci = c >> 1;
        h[(rowBase + rg * 4 + 0) * 32 + ci] = pack_bf16(a0, o0);
        h[(rowBase + rg * 4 + 1) * 32 + ci] = pack_bf16(a1, o1);
        h[(rowBase + rg * 4 + 2) * 32 + ci] = pack_bf16(a2, o2);
        h[(rowBase + rg * 4 + 3) * 32 + ci] = pack_bf16(a3, o3);
    }
}

// ---- CSR aggregate + fused epilogue (bf16 dis-scaled h rows, 128 B) ------
// one wave per node; 8 groups of 8 lanes, one edge per group per step,
// lane reads uint4 = 8 bf16 channels. out = dis_t*(acc + h'[t]) + b.
__global__ __launch_bounds__(256) void agg_kernel(const int* __restrict__ rowptr,
                                                  const EdgeRec* __restrict__ ed,
                                                  const unsigned* __restrict__ h,
                                                  const float* __restrict__ dis,
                                                  const float* __restrict__ b,
                                                  float* __restrict__ out,
                                                  int relu) {
    int node = blockIdx.x * 4 + (threadIdx.x >> 6);
    int lane = threadIdx.x & 63;
    int g = lane >> 3;        // edge group 0..7
    int cl = lane & 7;        // channel octet: channels 8*cl .. 8*cl+7
    int beg = rowptr[node];
    int end = rowptr[node + 1];
    const uint4* h16 = (const uint4*)h;   // 8 uint4 per 64-ch row
    float acc[8] = {0.f, 0.f, 0.f, 0.f, 0.f, 0.f, 0.f, 0.f};
    int e = beg + g;
    for (; e + 8 < end; e += 16) {
        EdgeRec r0 = ed[e];
        EdgeRec r1 = ed[e + 8];
        uint4 u0 = h16[r0.s * 8 + cl];
        uint4 u1 = h16[r1.s * 8 + cl];
        acc[0] += r0.v * bf_lo(u0.x); acc[1] += r0.v * bf_hi(u0.x);
        acc[2] += r0.v * bf_lo(u0.y); acc[3] += r0.v * bf_hi(u0.y);
        acc[4] += r0.v * bf_lo(u0.z); acc[5] += r0.v * bf_hi(u0.z);
        acc[6] += r0.v * bf_lo(u0.w); acc[7] += r0.v * bf_hi(u0.w);
        acc[0] += r1.v * bf_lo(u1.x); acc[1] += r1.v * bf_hi(u1.x);
        acc[2] += r1.v * bf_lo(u1.y); acc[3] += r1.v * bf_hi(u1.y);
        acc[4] += r1.v * bf_lo(u1.z); acc[5] += r1.v * bf_hi(u1.z);
        acc[6] += r1.v * bf_lo(u1.w); acc[7] += r1.v * bf_hi(u1.w);
    }
    if (e < end) {
        EdgeRec r0 = ed[e];
        uint4 u0 = h16[r0.s * 8 + cl];
        acc[0] += r0.v * bf_lo(u0.x); acc[1] += r0.v * bf_hi(u0.x);
        acc[2] += r0.v * bf_lo(u0.y); acc[3] += r0.v * bf_hi(u0.y);
        acc[4] += r0.v * bf_lo(u0.z); acc[5] += r0.v * bf_hi(u0.z);
        acc[6] += r0.v * bf_lo(u0.w); acc[7] += r0.v * bf_hi(u0.w);
    }
    #pragma unroll
    for (int k = 0; k < 8; ++k) {
        acc[k] += __shfl_xor(acc[k], 8, 64);
        acc[k] += __shfl_xor(acc[k], 16, 64);
        acc[k] += __shfl_xor(acc[k], 32, 64);
    }
    if (g == 0) {
        float d = dis[node];
        uint4 us = h16[node * 8 + cl];
        float hs[8] = { bf_lo(us.x), bf_hi(us.x), bf_lo(us.y), bf_hi(us.y),
                        bf_lo(us.z), bf_hi(us.z), bf_lo(us.w), bf_hi(us.w) };
        const float4* b4 = (const float4*)b;
        float4 bv0 = b4[cl * 2], bv1 = b4[cl * 2 + 1];
        float4 v0, v1;
        v0.x = d * (acc[0] + hs[0]) + bv0.x;
        v0.y = d * (acc[1] + hs[1]) + bv0.y;
        v0.z = d * (acc[2] + hs[2]) + bv0.z;
        v0.w = d * (acc[3] + hs[3]) + bv0.w;
        v1.x = d * (acc[4] + hs[4]) + bv1.x;
        v1.y = d * (acc[5] + hs[5]) + bv1.y;
        v1.z = d * (acc[6] + hs[6]) + bv1.z;
        v1.w = d * (acc[7] + hs[7]) + bv1.w;
        if (relu) {
            v0.x = fmaxf(v0.x, 0.f); v0.y = fmaxf(v0.y, 0.f);
            v0.z = fmaxf(v0.z, 0.f); v0.w = fmaxf(v0.w, 0.f);
            v1.x = fmaxf(v1.x, 0.f); v1.y = fmaxf(v1.y, 0.f);
            v1.z = fmaxf(v1.z, 0.f); v1.w = fmaxf(v1.w, 0.f);
        }
        float4* o4 = (float4*)out;
        o4[node * 16 + cl * 2]     = v0;
        o4[node * 16 + cl * 2 + 1] = v1;
    }
}

extern "C" void kernel_launch(void* const* d_in, const int* in_sizes, int n_in,
                              void* d_out, int out_size, void* d_ws, size_t ws_size,
                              hipStream_t stream) {
    const float* x  = (const float*)d_in[0];
    const int*   ei = (const int*)d_in[1];   // [2, E]: sources then targets
    const float* ew = (const float*)d_in[2];
    const float* W1 = (const float*)d_in[3];
    const float* b1 = (const float*)d_in[4];
    const float* W2 = (const float*)d_in[5];
    const float* b2 = (const float*)d_in[6];
    float* out = (float*)d_out;

    // workspace carve-up (256 B aligned). tmp (25.6 MB) is dead after
    // fine_sort; bf16 h (12.8 MB) + f32 a (25.6 MB) overlay it
    // (stream-ordered reuse). Total ~64.5 MB.
    char* p = (char*)d_ws;
    auto carve = [&](size_t bytes) { char* r = p; p += (bytes + 255) & ~(size_t)255; return r; };
    float*    dis     = (float*)carve(N_NODES * 4);
    int*      rowptr  = (int*)carve((N_NODES + 1) * 4);
    int*      gcnt    = (int*)carve(256 * 4);
    int*      start   = (int*)carve(257 * 4);
    int*      gcursor = (int*)carve(256 * 4);
    EdgeRec*  ed      = (EdgeRec*)carve((size_t)N_EDGES * 8);
    char*     r2      = carve((size_t)N_NODES * 64 * 2 + (size_t)N_NODES * 64 * 4);
    uint2*    tmp     = (uint2*)r2;                              // E*8 = 25.6 MB fits
    unsigned* h       = (unsigned*)r2;                           // N*64 bf16 = 12.8 MB
    float*    a       = (float*)(r2 + (size_t)N_NODES * 64 * 2); // N*64 f32 = 25.6 MB

    // --- CSR build (bucketed, no large-scale random global atomics) ---
    hipMemsetAsync(gcnt, 0, 256 * sizeof(int), stream);
    coarse_hist<<<CH_GRID, 256, 0, stream>>>(ei + N_EDGES, gcnt);
    coarse_scan<<<1, 256, 0, stream>>>(gcnt, start, gcursor);
    scatter_coarse<<<SC_GRID, 256, 0, stream>>>(ei, ew, gcursor, tmp);
    fine_sort<<<NBUCKET, 512, 0, stream>>>(start, tmp, rowptr, dis, ed);

    // --- layer 1: h = bf16(dis.(x@W1)) ; a = relu(agg(h) + b1) ---
    mm1_kernel<<<N_NODES / 16, 256, 0, stream>>>(x, W1, dis, h);
    agg_kernel<<<N_NODES / 4, 256, 0, stream>>>(rowptr, ed, h, dis, b1, a, 1);

    // --- layer 2: h = bf16(dis.(a@W2)) ; out = agg(h) + b2 ---
    mm2_kernel<<<N_NODES / 16, 256, 0, stream>>>(a, W2, dis, h);
    agg_kernel<<<N_NODES / 4, 256, 0, stream>>>(rowptr, ed, h, dis, b2, out, 0);
}

// Round 7
// 458.627 us; speedup vs baseline: 3.9203x; 1.0420x over previous
//
#include <hip/hip_runtime.h>
#include <hip/hip_bf16.h>

#define N_NODES 100000
#define N_EDGES 3200000
#define IN_C 128
#define HID_C 64
#define OUT_C 64

#define NBUCKET 196          // ceil(N_NODES / 512); bucket = target >> 9
#define CH_GRID 1563         // ceil(E / 2048) for coarse hist (256 thr x 8 edges)
#define SC_EDGES 4096        // edges per scatter block
#define SC_GRID 782          // ceil(E / SC_EDGES)

struct EdgeRec { int s; float v; };   // source node, raw edge weight w

// staged record: 8 B. x = f32 bits of w; y = s (17 bits) | t_local<<17 (9 bits)
__device__ __forceinline__ unsigned pack_bf16(float lo, float hi) {
    unsigned short l = __hip_bfloat16_raw(__float2bfloat16(lo)).x;
    unsigned short h = __hip_bfloat16_raw(__float2bfloat16(hi)).x;
    return ((unsigned)h << 16) | l;
}
__device__ __forceinline__ float bf_lo(unsigned u) {
    union { unsigned u; float f; } c; c.u = u << 16; return c.f;
}
__device__ __forceinline__ float bf_hi(unsigned u) {
    union { unsigned u; float f; } c; c.u = u & 0xffff0000u; return c.f;
}

// ---- coarse histogram: count edges per 512-node bucket -------------------
__global__ __launch_bounds__(256) void coarse_hist(const int* __restrict__ tgt,
                                                   int* __restrict__ gcnt) {
    __shared__ int hist[256];
    int tid = threadIdx.x;
    hist[tid] = 0;
    __syncthreads();
    int base = blockIdx.x * 2048;
    for (int i = 0; i < 8; ++i) {
        int e = base + i * 256 + tid;
        if (e < N_EDGES) atomicAdd(&hist[tgt[e] >> 9], 1);
    }
    __syncthreads();
    if (hist[tid]) atomicAdd(&gcnt[tid], hist[tid]);
}

// ---- exclusive scan of 256 bucket counts (single block) ------------------
__global__ __launch_bounds__(256) void coarse_scan(const int* __restrict__ gcnt,
                                                   int* __restrict__ start,
                                                   int* __restrict__ cursor) {
    __shared__ int s[256];
    int tid = threadIdx.x;
    int v = gcnt[tid];
    s[tid] = v;
    __syncthreads();
    for (int off = 1; off < 256; off <<= 1) {
        int t = s[tid];
        int add = (tid >= off) ? s[tid - off] : 0;
        __syncthreads();
        s[tid] = t + add;
        __syncthreads();
    }
    int excl = s[tid] - v;
    start[tid] = excl;
    cursor[tid] = excl;
    if (tid == 255) start[256] = s[255];   // == N_EDGES
}

// ---- coarse scatter: edges -> bucket-major order, 8-B packed records -----
// 4096 edges/block (parallelism), targets register-cached (one pass).
__global__ __launch_bounds__(256) void scatter_coarse(const int* __restrict__ ei,
                                                      const float* __restrict__ ew,
                                                      int* __restrict__ gcursor,
                                                      uint2* __restrict__ tmp) {
    __shared__ int hist[256];
    __shared__ int cur[256];
    int tid = threadIdx.x;
    hist[tid] = 0;
    __syncthreads();
    int base = blockIdx.x * SC_EDGES;
    int ts[16];
    for (int i = 0; i < 16; ++i) {
        int e = base + i * 256 + tid;
        if (e < N_EDGES) {
            int t = ei[N_EDGES + e];
            ts[i] = t;
            atomicAdd(&hist[t >> 9], 1);
        } else ts[i] = -1;
    }
    __syncthreads();
    cur[tid] = atomicAdd(&gcursor[tid], hist[tid]);
    __syncthreads();
    for (int i = 0; i < 16; ++i) {
        if (ts[i] >= 0) {
            int e = base + i * 256 + tid;
            int b = ts[i] >> 9;
            int pos = atomicAdd(&cur[b], 1);
            uint2 r;
            r.x = __float_as_uint(ew[e]);
            r.y = (unsigned)ei[e] | ((unsigned)(ts[i] & 511) << 17);
            tmp[pos] = r;
        }
    }
}

// ---- per-bucket counting sort + rowptr + dis (one block per bucket) ------
__global__ __launch_bounds__(512) void fine_sort(const int* __restrict__ start,
                                                 const uint2* __restrict__ tmp,
                                                 int* __restrict__ rowptr,
                                                 float* __restrict__ dis,
                                                 EdgeRec* __restrict__ ed) {
    __shared__ int   cnt[512];
    __shared__ float wdeg[512];
    __shared__ int   s[512];
    int tid = threadIdx.x;
    int nodeBase = blockIdx.x << 9;
    int bb = start[blockIdx.x];
    int be = start[blockIdx.x + 1];
    cnt[tid] = 0;
    wdeg[tid] = 0.f;
    __syncthreads();
    for (int e = bb + tid; e < be; e += 512) {
        uint2 r = tmp[e];
        int l = (r.y >> 17) & 511;
        atomicAdd(&cnt[l], 1);
        atomicAdd(&wdeg[l], __uint_as_float(r.x));
    }
    __syncthreads();
    int v = cnt[tid];
    s[tid] = v;
    __syncthreads();
    for (int off = 1; off < 512; off <<= 1) {
        int t = s[tid];
        int add = (tid >= off) ? s[tid - off] : 0;
        __syncthreads();
        s[tid] = t + add;
        __syncthreads();
    }
    int excl = s[tid] - v;
    int node = nodeBase + tid;
    if (node < N_NODES) {
        rowptr[node] = bb + excl;
        dis[node] = rsqrtf(wdeg[tid] + 1.0f);   // +1 = self-loop weight
    }
    if (node == N_NODES) rowptr[N_NODES] = N_EDGES;
    cnt[tid] = excl;       // reuse as cursor
    __syncthreads();
    for (int e = bb + tid; e < be; e += 512) {
        uint2 r = tmp[e];
        int l = (r.y >> 17) & 511;
        int p = atomicAdd(&cnt[l], 1);
        EdgeRec o;
        o.s = (int)(r.y & 0x1FFFFu);
        o.v = __uint_as_float(r.x);
        ed[bb + p] = o;
    }
}

// ---- h = bf16( dis[row] * (x @ W1) )   [N,128] @ [128,64] ----------------
// dis-scaling folded here removes the fixup pass: GCN update becomes
// out[t] = dis_t * (sum_e w_e * h'[s_e] + h'[t]) + b, with h' = dis.h.
__global__ __launch_bounds__(256) void mm1_kernel(const float* __restrict__ x,
                                                  const float* __restrict__ W,
                                                  const float* __restrict__ dis,
                                                  unsigned* __restrict__ h) {
    __shared__ float xs[16][IN_C];      // 8 KB
    __shared__ float wsm[IN_C][HID_C];  // 32 KB
    int tid = threadIdx.x;
    // both stages are contiguous copies -> float4
    {
        float4*       wd = (float4*)&wsm[0][0];
        const float4* wsrc = (const float4*)W;
        for (int i = tid; i < IN_C * HID_C / 4; i += 256) wd[i] = wsrc[i];
        float4*       xd = (float4*)&xs[0][0];
        const float4* xsrc = (const float4*)(x + (size_t)blockIdx.x * 16 * IN_C);
        for (int i = tid; i < 16 * IN_C / 4; i += 256) xd[i] = xsrc[i];
    }
    int rowBase = blockIdx.x * 16;
    __syncthreads();
    int c = tid & 63, rg = tid >> 6;
    float a0 = 0.f, a1 = 0.f, a2 = 0.f, a3 = 0.f;
    for (int k = 0; k < IN_C; ++k) {
        float wv = wsm[k][c];
        a0 += xs[rg * 4 + 0][k] * wv;
        a1 += xs[rg * 4 + 1][k] * wv;
        a2 += xs[rg * 4 + 2][k] * wv;
        a3 += xs[rg * 4 + 3][k] * wv;
    }
    a0 *= dis[rowBase + rg * 4 + 0];
    a1 *= dis[rowBase + rg * 4 + 1];
    a2 *= dis[rowBase + rg * 4 + 2];
    a3 *= dis[rowBase + rg * 4 + 3];
    float o0 = __shfl_xor(a0, 1, 64);
    float o1 = __shfl_xor(a1, 1, 64);
    float o2 = __shfl_xor(a2, 1, 64);
    float o3 = __shfl_xor(a3, 1, 64);
    if ((c & 1) == 0) {
        int ci = c >> 1;
        h[(rowBase + rg * 4 + 0) * 32 + ci] = pack_bf16(a0, o0);
        h[(rowBase + rg * 4 + 1) * 32 + ci] = pack_bf16(a1, o1);
        h[(rowBase + rg * 4 + 2) * 32 + ci] = pack_bf16(a2, o2);
        h[(rowBase + rg * 4 + 3) * 32 + ci] = pack_bf16(a3, o3);
    }
}

// ---- h = bf16( dis[row] * (a @ W2) )   [N,64] @ [64,64] ------------------
__global__ __launch_bounds__(256) void mm2_kernel(const float* __restrict__ a,
                                                  const float* __restrict__ W,
                                                  const float* __restrict__ dis,
                                                  unsigned* __restrict__ h) {
    __shared__ float as[16][HID_C];      // 4 KB
    __shared__ float wsm[HID_C][OUT_C];  // 16 KB
    int tid = threadIdx.x;
    {
        float4*       wd = (float4*)&wsm[0][0];
        const float4* wsrc = (const float4*)W;
        for (int i = tid; i < HID_C * OUT_C / 4; i += 256) wd[i] = wsrc[i];
        float4*       ad = (float4*)&as[0][0];
        const float4* asrc = (const float4*)(a + (size_t)blockIdx.x * 16 * HID_C);
        for (int i = tid; i < 16 * HID_C / 4; i += 256) ad[i] = asrc[i];
    }
    int rowBase = blockIdx.x * 16;
    __syncthreads();
    int c = tid & 63, rg = tid >> 6;
    float a0 = 0.f, a1 = 0.f, a2 = 0.f, a3 = 0.f;
    for (int k = 0; k < HID_C; ++k) {
        float wv = wsm[k][c];
        a0 += as[rg * 4 + 0][k] * wv;
        a1 += as[rg * 4 + 1][k] * wv;
        a2 += as[rg * 4 + 2][k] * wv;
        a3 += as[rg * 4 + 3][k] * wv;
    }
    a0 *= dis[rowBase + rg * 4 + 0];
    a1 *= dis[rowBase + rg * 4 + 1];
    a2 *= dis[rowBase + rg * 4 + 2];
    a3 *= dis[rowBase + rg * 4 + 3];
    float o0 = __shfl_xor(a0, 1, 64);
    float o1 = __shfl_xor(a1, 1, 64);
    float o2 = __shfl_xor(a2, 1, 64);
    float o3 = __shfl_xor(a3, 1, 64);
    if ((c & 1) == 0) {
        int ci = c >> 1;
        h[(rowBase + rg * 4 + 0) * 32 + ci] = pack_bf16(a0, o0);
        h[(rowBase + rg * 4 + 1) * 32 + ci] = pack_bf16(a1, o1);
        h[(rowBase + rg * 4 + 2) * 32 + ci] = pack_bf16(a2, o2);
        h[(rowBase + rg * 4 + 3) * 32 + ci] = pack_bf16(a3, o3);
    }
}

// ---- CSR aggregate + fused epilogue (bf16 dis-scaled h rows, 128 B) ------
// one wave per node; 8 groups of 8 lanes, one edge per group per step,
// lane reads uint4 = 8 bf16 channels. out = dis_t*(acc + h'[t]) + b.
__global__ __launch_bounds__(256) void agg_kernel(const int* __restrict__ rowptr,
                                                  const EdgeRec* __restrict__ ed,
                                                  const unsigned* __restrict__ h,
                                                  const float* __restrict__ dis,
                                                  const float* __restrict__ b,
                                                  float* __restrict__ out,
                                                  int relu) {
    int node = blockIdx.x * 4 + (threadIdx.x >> 6);
    int lane = threadIdx.x & 63;
    int g = lane >> 3;        // edge group 0..7
    int cl = lane & 7;        // channel octet: channels 8*cl .. 8*cl+7
    int beg = rowptr[node];
    int end = rowptr[node + 1];
    const uint4* h16 = (const uint4*)h;   // 8 uint4 per 64-ch row
    float acc[8] = {0.f, 0.f, 0.f, 0.f, 0.f, 0.f, 0.f, 0.f};
    int e = beg + g;
    for (; e + 8 < end; e += 16) {
        EdgeRec r0 = ed[e];
        EdgeRec r1 = ed[e + 8];
        uint4 u0 = h16[r0.s * 8 + cl];
        uint4 u1 = h16[r1.s * 8 + cl];
        acc[0] += r0.v * bf_lo(u0.x); acc[1] += r0.v * bf_hi(u0.x);
        acc[2] += r0.v * bf_lo(u0.y); acc[3] += r0.v * bf_hi(u0.y);
        acc[4] += r0.v * bf_lo(u0.z); acc[5] += r0.v * bf_hi(u0.z);
        acc[6] += r0.v * bf_lo(u0.w); acc[7] += r0.v * bf_hi(u0.w);
        acc[0] += r1.v * bf_lo(u1.x); acc[1] += r1.v * bf_hi(u1.x);
        acc[2] += r1.v * bf_lo(u1.y); acc[3] += r1.v * bf_hi(u1.y);
        acc[4] += r1.v * bf_lo(u1.z); acc[5] += r1.v * bf_hi(u1.z);
        acc[6] += r1.v * bf_lo(u1.w); acc[7] += r1.v * bf_hi(u1.w);
    }
    if (e < end) {
        EdgeRec r0 = ed[e];
        uint4 u0 = h16[r0.s * 8 + cl];
        acc[0] += r0.v * bf_lo(u0.x); acc[1] += r0.v * bf_hi(u0.x);
        acc[2] += r0.v * bf_lo(u0.y); acc[3] += r0.v * bf_hi(u0.y);
        acc[4] += r0.v * bf_lo(u0.z); acc[5] += r0.v * bf_hi(u0.z);
        acc[6] += r0.v * bf_lo(u0.w); acc[7] += r0.v * bf_hi(u0.w);
    }
    #pragma unroll
    for (int k = 0; k < 8; ++k) {
        acc[k] += __shfl_xor(acc[k], 8, 64);
        acc[k] += __shfl_xor(acc[k], 16, 64);
        acc[k] += __shfl_xor(acc[k], 32, 64);
    }
    if (g == 0) {
        float d = dis[node];
        uint4 us = h16[node * 8 + cl];
        float hs[8] = { bf_lo(us.x), bf_hi(us.x), bf_lo(us.y), bf_hi(us.y),
                        bf_lo(us.z), bf_hi(us.z), bf_lo(us.w), bf_hi(us.w) };
        const float4* b4 = (const float4*)b;
        float4 bv0 = b4[cl * 2], bv1 = b4[cl * 2 + 1];
        float4 v0, v1;
        v0.x = d * (acc[0] + hs[0]) + bv0.x;
        v0.y = d * (acc[1] + hs[1]) + bv0.y;
        v0.z = d * (acc[2] + hs[2]) + bv0.z;
        v0.w = d * (acc[3] + hs[3]) + bv0.w;
        v1.x = d * (acc[4] + hs[4]) + bv1.x;
        v1.y = d * (acc[5] + hs[5]) + bv1.y;
        v1.z = d * (acc[6] + hs[6]) + bv1.z;
        v1.w = d * (acc[7] + hs[7]) + bv1.w;
        if (relu) {
            v0.x = fmaxf(v0.x, 0.f); v0.y = fmaxf(v0.y, 0.f);
            v0.z = fmaxf(v0.z, 0.f); v0.w = fmaxf(v0.w, 0.f);
            v1.x = fmaxf(v1.x, 0.f); v1.y = fmaxf(v1.y, 0.f);
            v1.z = fmaxf(v1.z, 0.f); v1.w = fmaxf(v1.w, 0.f);
        }
        float4* o4 = (float4*)out;
        o4[node * 16 + cl * 2]     = v0;
        o4[node * 16 + cl * 2 + 1] = v1;
    }
}

extern "C" void kernel_launch(void* const* d_in, const int* in_sizes, int n_in,
                              void* d_out, int out_size, void* d_ws, size_t ws_size,
                              hipStream_t stream) {
    const float* x  = (const float*)d_in[0];
    const int*   ei = (const int*)d_in[1];   // [2, E]: sources then targets
    const float* ew = (const float*)d_in[2];
    const float* W1 = (const float*)d_in[3];
    const float* b1 = (const float*)d_in[4];
    const float* W2 = (const float*)d_in[5];
    const float* b2 = (const float*)d_in[6];
    float* out = (float*)d_out;

    // workspace carve-up (256 B aligned). tmp (25.6 MB) is dead after
    // fine_sort; bf16 h (12.8 MB) + f32 a (25.6 MB) overlay it
    // (stream-ordered reuse). Total ~64.5 MB.
    char* p = (char*)d_ws;
    auto carve = [&](size_t bytes) { char* r = p; p += (bytes + 255) & ~(size_t)255; return r; };
    float*    dis     = (float*)carve(N_NODES * 4);
    int*      rowptr  = (int*)carve((N_NODES + 1) * 4);
    int*      gcnt    = (int*)carve(256 * 4);
    int*      start   = (int*)carve(257 * 4);
    int*      gcursor = (int*)carve(256 * 4);
    EdgeRec*  ed      = (EdgeRec*)carve((size_t)N_EDGES * 8);
    char*     r2      = carve((size_t)N_NODES * 64 * 2 + (size_t)N_NODES * 64 * 4);
    uint2*    tmp     = (uint2*)r2;                              // E*8 = 25.6 MB fits
    unsigned* h       = (unsigned*)r2;                           // N*64 bf16 = 12.8 MB
    float*    a       = (float*)(r2 + (size_t)N_NODES * 64 * 2); // N*64 f32 = 25.6 MB

    // --- CSR build (bucketed, no large-scale random global atomics) ---
    hipMemsetAsync(gcnt, 0, 256 * sizeof(int), stream);
    coarse_hist<<<CH_GRID, 256, 0, stream>>>(ei + N_EDGES, gcnt);
    coarse_scan<<<1, 256, 0, stream>>>(gcnt, start, gcursor);
    scatter_coarse<<<SC_GRID, 256, 0, stream>>>(ei, ew, gcursor, tmp);
    fine_sort<<<NBUCKET, 512, 0, stream>>>(start, tmp, rowptr, dis, ed);

    // --- layer 1: h = bf16(dis.(x@W1)) ; a = relu(agg(h) + b1) ---
    mm1_kernel<<<N_NODES / 16, 256, 0, stream>>>(x, W1, dis, h);
    agg_kernel<<<N_NODES / 4, 256, 0, stream>>>(rowptr, ed, h, dis, b1, a, 1);

    // --- layer 2: h = bf16(dis.(a@W2)) ; out = agg(h) + b2 ---
    mm2_kernel<<<N_NODES / 16, 256, 0, stream>>>(a, W2, dis, h);
    agg_kernel<<<N_NODES / 4, 256, 0, stream>>>(rowptr, ed, h, dis, b2, out, 0);
}

// Round 8
// 418.175 us; speedup vs baseline: 4.2995x; 1.0967x over previous
//
#include <hip/hip_runtime.h>
#include <hip/hip_bf16.h>

#define N_NODES 100000
#define N_EDGES 3200000
#define IN_C 128
#define HID_C 64
#define OUT_C 64

#define NBUCKET 196          // ceil(N_NODES / 512); bucket = target >> 9
#define CH_GRID 1563         // ceil(E / 2048) for coarse hist (256 thr x 8 edges)
#define SC_EDGES 4096        // edges per scatter block
#define SC_GRID 782          // ceil(E / SC_EDGES)

struct EdgeRec { int s; float v; };   // source node, raw edge weight w

// staged record: 8 B. x = f32 bits of w; y = s (17 bits) | t_local<<17 (9 bits)
__device__ __forceinline__ unsigned pack_bf16(float lo, float hi) {
    unsigned short l = __hip_bfloat16_raw(__float2bfloat16(lo)).x;
    unsigned short h = __hip_bfloat16_raw(__float2bfloat16(hi)).x;
    return ((unsigned)h << 16) | l;
}
__device__ __forceinline__ float bf_lo(unsigned u) {
    union { unsigned u; float f; } c; c.u = u << 16; return c.f;
}
__device__ __forceinline__ float bf_hi(unsigned u) {
    union { unsigned u; float f; } c; c.u = u & 0xffff0000u; return c.f;
}

// ---- coarse histogram: count edges per 512-node bucket -------------------
__global__ __launch_bounds__(256) void coarse_hist(const int* __restrict__ tgt,
                                                   int* __restrict__ gcnt) {
    __shared__ int hist[256];
    int tid = threadIdx.x;
    hist[tid] = 0;
    __syncthreads();
    int base = blockIdx.x * 2048;
    for (int i = 0; i < 8; ++i) {
        int e = base + i * 256 + tid;
        if (e < N_EDGES) atomicAdd(&hist[tgt[e] >> 9], 1);
    }
    __syncthreads();
    if (hist[tid]) atomicAdd(&gcnt[tid], hist[tid]);
}

// ---- exclusive scan of 256 bucket counts (single block) ------------------
__global__ __launch_bounds__(256) void coarse_scan(const int* __restrict__ gcnt,
                                                   int* __restrict__ start,
                                                   int* __restrict__ cursor) {
    __shared__ int s[256];
    int tid = threadIdx.x;
    int v = gcnt[tid];
    s[tid] = v;
    __syncthreads();
    for (int off = 1; off < 256; off <<= 1) {
        int t = s[tid];
        int add = (tid >= off) ? s[tid - off] : 0;
        __syncthreads();
        s[tid] = t + add;
        __syncthreads();
    }
    int excl = s[tid] - v;
    start[tid] = excl;
    cursor[tid] = excl;
    if (tid == 255) start[256] = s[255];   // == N_EDGES
}

// ---- coarse scatter v3: in-block LDS counting sort, run-coalesced writes --
// Sort 4096 edges bucket-major in LDS, then consecutive threads write
// consecutive global addresses within each bucket run (few lines per wave
// instead of 64 scattered lines).
__global__ __launch_bounds__(256) void scatter_coarse(const int* __restrict__ ei,
                                                      const float* __restrict__ ew,
                                                      int* __restrict__ gcursor,
                                                      uint2* __restrict__ tmp) {
    __shared__ int hist[256];
    __shared__ int scan[256];
    __shared__ int lcur[256];
    __shared__ int adj[256];
    __shared__ uint2 rec[SC_EDGES];           // 32 KB
    __shared__ unsigned char bk[SC_EDGES];    // 4 KB
    int tid = threadIdx.x;
    hist[tid] = 0;
    __syncthreads();
    int base = blockIdx.x * SC_EDGES;
    unsigned ys[16];
    float    ws[16];
    int      bs[16];
    for (int i = 0; i < 16; ++i) {
        int e = base + i * 256 + tid;
        if (e < N_EDGES) {
            int t = ei[N_EDGES + e];
            bs[i] = t >> 9;
            ys[i] = (unsigned)ei[e] | ((unsigned)(t & 511) << 17);
            ws[i] = ew[e];
            atomicAdd(&hist[bs[i]], 1);
        } else bs[i] = -1;
    }
    __syncthreads();
    // exclusive scan of hist
    int v = hist[tid];
    scan[tid] = v;
    __syncthreads();
    for (int off = 1; off < 256; off <<= 1) {
        int t = scan[tid];
        int add = (tid >= off) ? scan[tid - off] : 0;
        __syncthreads();
        scan[tid] = t + add;
        __syncthreads();
    }
    int excl = scan[tid] - v;
    int gb = (v > 0) ? atomicAdd(&gcursor[tid], v) : 0;
    lcur[tid] = excl;
    adj[tid] = gb - excl;     // global slot for LDS slot j of bucket b: adj[b]+j
    __syncthreads();
    // place edges into LDS bucket-major
    for (int i = 0; i < 16; ++i) {
        if (bs[i] >= 0) {
            int j = atomicAdd(&lcur[bs[i]], 1);
            rec[j] = make_uint2(__float_as_uint(ws[i]), ys[i]);
            bk[j] = (unsigned char)bs[i];
        }
    }
    __syncthreads();
    // run-coalesced write-out
    int count = N_EDGES - base;
    if (count > SC_EDGES) count = SC_EDGES;
    for (int j = tid; j < count; j += 256) {
        int b = bk[j];
        tmp[adj[b] + j] = rec[j];
    }
}

// ---- per-bucket counting sort + rowptr + dis (one block per bucket) ------
__global__ __launch_bounds__(512) void fine_sort(const int* __restrict__ start,
                                                 const uint2* __restrict__ tmp,
                                                 int* __restrict__ rowptr,
                                                 float* __restrict__ dis,
                                                 EdgeRec* __restrict__ ed) {
    __shared__ int   cnt[512];
    __shared__ float wdeg[512];
    __shared__ int   s[512];
    int tid = threadIdx.x;
    int nodeBase = blockIdx.x << 9;
    int bb = start[blockIdx.x];
    int be = start[blockIdx.x + 1];
    cnt[tid] = 0;
    wdeg[tid] = 0.f;
    __syncthreads();
    for (int e = bb + tid; e < be; e += 512) {
        uint2 r = tmp[e];
        int l = (r.y >> 17) & 511;
        atomicAdd(&cnt[l], 1);
        atomicAdd(&wdeg[l], __uint_as_float(r.x));
    }
    __syncthreads();
    int v = cnt[tid];
    s[tid] = v;
    __syncthreads();
    for (int off = 1; off < 512; off <<= 1) {
        int t = s[tid];
        int add = (tid >= off) ? s[tid - off] : 0;
        __syncthreads();
        s[tid] = t + add;
        __syncthreads();
    }
    int excl = s[tid] - v;
    int node = nodeBase + tid;
    if (node < N_NODES) {
        rowptr[node] = bb + excl;
        dis[node] = rsqrtf(wdeg[tid] + 1.0f);   // +1 = self-loop weight
    }
    if (node == N_NODES) rowptr[N_NODES] = N_EDGES;
    cnt[tid] = excl;       // reuse as cursor
    __syncthreads();
    for (int e = bb + tid; e < be; e += 512) {
        uint2 r = tmp[e];
        int l = (r.y >> 17) & 511;
        int p = atomicAdd(&cnt[l], 1);
        EdgeRec o;
        o.s = (int)(r.y & 0x1FFFFu);
        o.v = __uint_as_float(r.x);
        ed[bb + p] = o;
    }
}

// ---- h = bf16( dis[row] * (x @ W1) )   [N,128] @ [128,64] ----------------
__global__ __launch_bounds__(256) void mm1_kernel(const float* __restrict__ x,
                                                  const float* __restrict__ W,
                                                  const float* __restrict__ dis,
                                                  unsigned* __restrict__ h) {
    __shared__ float xs[16][IN_C];      // 8 KB
    __shared__ float wsm[IN_C][HID_C];  // 32 KB
    int tid = threadIdx.x;
    {
        float4*       wd = (float4*)&wsm[0][0];
        const float4* wsrc = (const float4*)W;
        for (int i = tid; i < IN_C * HID_C / 4; i += 256) wd[i] = wsrc[i];
        float4*       xd = (float4*)&xs[0][0];
        const float4* xsrc = (const float4*)(x + (size_t)blockIdx.x * 16 * IN_C);
        for (int i = tid; i < 16 * IN_C / 4; i += 256) xd[i] = xsrc[i];
    }
    int rowBase = blockIdx.x * 16;
    __syncthreads();
    int c = tid & 63, rg = tid >> 6;
    float a0 = 0.f, a1 = 0.f, a2 = 0.f, a3 = 0.f;
    for (int k = 0; k < IN_C; ++k) {
        float wv = wsm[k][c];
        a0 += xs[rg * 4 + 0][k] * wv;
        a1 += xs[rg * 4 + 1][k] * wv;
        a2 += xs[rg * 4 + 2][k] * wv;
        a3 += xs[rg * 4 + 3][k] * wv;
    }
    a0 *= dis[rowBase + rg * 4 + 0];
    a1 *= dis[rowBase + rg * 4 + 1];
    a2 *= dis[rowBase + rg * 4 + 2];
    a3 *= dis[rowBase + rg * 4 + 3];
    float o0 = __shfl_xor(a0, 1, 64);
    float o1 = __shfl_xor(a1, 1, 64);
    float o2 = __shfl_xor(a2, 1, 64);
    float o3 = __shfl_xor(a3, 1, 64);
    if ((c & 1) == 0) {
        int ci = c >> 1;
        h[(rowBase + rg * 4 + 0) * 32 + ci] = pack_bf16(a0, o0);
        h[(rowBase + rg * 4 + 1) * 32 + ci] = pack_bf16(a1, o1);
        h[(rowBase + rg * 4 + 2) * 32 + ci] = pack_bf16(a2, o2);
        h[(rowBase + rg * 4 + 3) * 32 + ci] = pack_bf16(a3, o3);
    }
}

// ---- h = bf16( dis[row] * (a @ W2) )   [N,64] @ [64,64] ------------------
__global__ __launch_bounds__(256) void mm2_kernel(const float* __restrict__ a,
                                                  const float* __restrict__ W,
                                                  const float* __restrict__ dis,
                                                  unsigned* __restrict__ h) {
    __shared__ float as[16][HID_C];      // 4 KB
    __shared__ float wsm[HID_C][OUT_C];  // 16 KB
    int tid = threadIdx.x;
    {
        float4*       wd = (float4*)&wsm[0][0];
        const float4* wsrc = (const float4*)W;
        for (int i = tid; i < HID_C * OUT_C / 4; i += 256) wd[i] = wsrc[i];
        float4*       ad = (float4*)&as[0][0];
        const float4* asrc = (const float4*)(a + (size_t)blockIdx.x * 16 * HID_C);
        for (int i = tid; i < 16 * HID_C / 4; i += 256) ad[i] = asrc[i];
    }
    int rowBase = blockIdx.x * 16;
    __syncthreads();
    int c = tid & 63, rg = tid >> 6;
    float a0 = 0.f, a1 = 0.f, a2 = 0.f, a3 = 0.f;
    for (int k = 0; k < HID_C; ++k) {
        float wv = wsm[k][c];
        a0 += as[rg * 4 + 0][k] * wv;
        a1 += as[rg * 4 + 1][k] * wv;
        a2 += as[rg * 4 + 2][k] * wv;
        a3 += as[rg * 4 + 3][k] * wv;
    }
    a0 *= dis[rowBase + rg * 4 + 0];
    a1 *= dis[rowBase + rg * 4 + 1];
    a2 *= dis[rowBase + rg * 4 + 2];
    a3 *= dis[rowBase + rg * 4 + 3];
    float o0 = __shfl_xor(a0, 1, 64);
    float o1 = __shfl_xor(a1, 1, 64);
    float o2 = __shfl_xor(a2, 1, 64);
    float o3 = __shfl_xor(a3, 1, 64);
    if ((c & 1) == 0) {
        int ci = c >> 1;
        h[(rowBase + rg * 4 + 0) * 32 + ci] = pack_bf16(a0, o0);
        h[(rowBase + rg * 4 + 1) * 32 + ci] = pack_bf16(a1, o1);
        h[(rowBase + rg * 4 + 2) * 32 + ci] = pack_bf16(a2, o2);
        h[(rowBase + rg * 4 + 3) * 32 + ci] = pack_bf16(a3, o3);
    }
}

// ---- CSR aggregate + fused epilogue (bf16 dis-scaled h rows, 128 B) ------
__global__ __launch_bounds__(256) void agg_kernel(const int* __restrict__ rowptr,
                                                  const EdgeRec* __restrict__ ed,
                                                  const unsigned* __restrict__ h,
                                                  const float* __restrict__ dis,
                                                  const float* __restrict__ b,
                                                  float* __restrict__ out,
                                                  int relu) {
    int node = blockIdx.x * 4 + (threadIdx.x >> 6);
    int lane = threadIdx.x & 63;
    int g = lane >> 3;        // edge group 0..7
    int cl = lane & 7;        // channel octet: channels 8*cl .. 8*cl+7
    int beg = rowptr[node];
    int end = rowptr[node + 1];
    const uint4* h16 = (const uint4*)h;   // 8 uint4 per 64-ch row
    float acc[8] = {0.f, 0.f, 0.f, 0.f, 0.f, 0.f, 0.f, 0.f};
    int e = beg + g;
    for (; e + 8 < end; e += 16) {
        EdgeRec r0 = ed[e];
        EdgeRec r1 = ed[e + 8];
        uint4 u0 = h16[r0.s * 8 + cl];
        uint4 u1 = h16[r1.s * 8 + cl];
        acc[0] += r0.v * bf_lo(u0.x); acc[1] += r0.v * bf_hi(u0.x);
        acc[2] += r0.v * bf_lo(u0.y); acc[3] += r0.v * bf_hi(u0.y);
        acc[4] += r0.v * bf_lo(u0.z); acc[5] += r0.v * bf_hi(u0.z);
        acc[6] += r0.v * bf_lo(u0.w); acc[7] += r0.v * bf_hi(u0.w);
        acc[0] += r1.v * bf_lo(u1.x); acc[1] += r1.v * bf_hi(u1.x);
        acc[2] += r1.v * bf_lo(u1.y); acc[3] += r1.v * bf_hi(u1.y);
        acc[4] += r1.v * bf_lo(u1.z); acc[5] += r1.v * bf_hi(u1.z);
        acc[6] += r1.v * bf_lo(u1.w); acc[7] += r1.v * bf_hi(u1.w);
    }
    if (e < end) {
        EdgeRec r0 = ed[e];
        uint4 u0 = h16[r0.s * 8 + cl];
        acc[0] += r0.v * bf_lo(u0.x); acc[1] += r0.v * bf_hi(u0.x);
        acc[2] += r0.v * bf_lo(u0.y); acc[3] += r0.v * bf_hi(u0.y);
        acc[4] += r0.v * bf_lo(u0.z); acc[5] += r0.v * bf_hi(u0.z);
        acc[6] += r0.v * bf_lo(u0.w); acc[7] += r0.v * bf_hi(u0.w);
    }
    #pragma unroll
    for (int k = 0; k < 8; ++k) {
        acc[k] += __shfl_xor(acc[k], 8, 64);
        acc[k] += __shfl_xor(acc[k], 16, 64);
        acc[k] += __shfl_xor(acc[k], 32, 64);
    }
    if (g == 0) {
        float d = dis[node];
        uint4 us = h16[node * 8 + cl];
        float hs[8] = { bf_lo(us.x), bf_hi(us.x), bf_lo(us.y), bf_hi(us.y),
                        bf_lo(us.z), bf_hi(us.z), bf_lo(us.w), bf_hi(us.w) };
        const float4* b4 = (const float4*)b;
        float4 bv0 = b4[cl * 2], bv1 = b4[cl * 2 + 1];
        float4 v0, v1;
        v0.x = d * (acc[0] + hs[0]) + bv0.x;
        v0.y = d * (acc[1] + hs[1]) + bv0.y;
        v0.z = d * (acc[2] + hs[2]) + bv0.z;
        v0.w = d * (acc[3] + hs[3]) + bv0.w;
        v1.x = d * (acc[4] + hs[4]) + bv1.x;
        v1.y = d * (acc[5] + hs[5]) + bv1.y;
        v1.z = d * (acc[6] + hs[6]) + bv1.z;
        v1.w = d * (acc[7] + hs[7]) + bv1.w;
        if (relu) {
            v0.x = fmaxf(v0.x, 0.f); v0.y = fmaxf(v0.y, 0.f);
            v0.z = fmaxf(v0.z, 0.f); v0.w = fmaxf(v0.w, 0.f);
            v1.x = fmaxf(v1.x, 0.f); v1.y = fmaxf(v1.y, 0.f);
            v1.z = fmaxf(v1.z, 0.f); v1.w = fmaxf(v1.w, 0.f);
        }
        float4* o4 = (float4*)out;
        o4[node * 16 + cl * 2]     = v0;
        o4[node * 16 + cl * 2 + 1] = v1;
    }
}

extern "C" void kernel_launch(void* const* d_in, const int* in_sizes, int n_in,
                              void* d_out, int out_size, void* d_ws, size_t ws_size,
                              hipStream_t stream) {
    const float* x  = (const float*)d_in[0];
    const int*   ei = (const int*)d_in[1];   // [2, E]: sources then targets
    const float* ew = (const float*)d_in[2];
    const float* W1 = (const float*)d_in[3];
    const float* b1 = (const float*)d_in[4];
    const float* W2 = (const float*)d_in[5];
    const float* b2 = (const float*)d_in[6];
    float* out = (float*)d_out;

    // workspace carve-up (256 B aligned). tmp (25.6 MB) is dead after
    // fine_sort; bf16 h (12.8 MB) + f32 a (25.6 MB) overlay it.
    char* p = (char*)d_ws;
    auto carve = [&](size_t bytes) { char* r = p; p += (bytes + 255) & ~(size_t)255; return r; };
    float*    dis     = (float*)carve(N_NODES * 4);
    int*      rowptr  = (int*)carve((N_NODES + 1) * 4);
    int*      gcnt    = (int*)carve(256 * 4);
    int*      start   = (int*)carve(257 * 4);
    int*      gcursor = (int*)carve(256 * 4);
    EdgeRec*  ed      = (EdgeRec*)carve((size_t)N_EDGES * 8);
    char*     r2      = carve((size_t)N_NODES * 64 * 2 + (size_t)N_NODES * 64 * 4);
    uint2*    tmp     = (uint2*)r2;                              // E*8 = 25.6 MB fits
    unsigned* h       = (unsigned*)r2;                           // N*64 bf16 = 12.8 MB
    float*    a       = (float*)(r2 + (size_t)N_NODES * 64 * 2); // N*64 f32 = 25.6 MB

    // --- CSR build (bucketed, no large-scale random global atomics) ---
    hipMemsetAsync(gcnt, 0, 256 * sizeof(int), stream);
    coarse_hist<<<CH_GRID, 256, 0, stream>>>(ei + N_EDGES, gcnt);
    coarse_scan<<<1, 256, 0, stream>>>(gcnt, start, gcursor);
    scatter_coarse<<<SC_GRID, 256, 0, stream>>>(ei, ew, gcursor, tmp);
    fine_sort<<<NBUCKET, 512, 0, stream>>>(start, tmp, rowptr, dis, ed);

    // --- layer 1: h = bf16(dis.(x@W1)) ; a = relu(agg(h) + b1) ---
    mm1_kernel<<<N_NODES / 16, 256, 0, stream>>>(x, W1, dis, h);
    agg_kernel<<<N_NODES / 4, 256, 0, stream>>>(rowptr, ed, h, dis, b1, a, 1);

    // --- layer 2: h = bf16(dis.(a@W2)) ; out = agg(h) + b2 ---
    mm2_kernel<<<N_NODES / 16, 256, 0, stream>>>(a, W2, dis, h);
    agg_kernel<<<N_NODES / 4, 256, 0, stream>>>(rowptr, ed, h, dis, b2, out, 0);
}

// Round 9
// 392.090 us; speedup vs baseline: 4.5856x; 1.0665x over previous
//
#include <hip/hip_runtime.h>
#include <hip/hip_bf16.h>

#define N_NODES 100000
#define N_EDGES 3200000
#define IN_C 128
#define HID_C 64
#define OUT_C 64

#define NBUCKET 196          // ceil(N_NODES / 512); bucket = target >> 9
#define SC_EDGES 4096        // edges per scatter block
#define SC_GRID 782          // ceil(E / SC_EDGES)
#define CAP 18432            // padded bucket capacity (mean 16384 + 16 sigma)

struct EdgeRec { int s; float v; };   // source node, raw edge weight w

// staged record: 8 B. x = f32 bits of w; y = s (17 bits) | t_local<<17 (9 bits)
__device__ __forceinline__ unsigned pack_bf16(float lo, float hi) {
    unsigned short l = __hip_bfloat16_raw(__float2bfloat16(lo)).x;
    unsigned short h = __hip_bfloat16_raw(__float2bfloat16(hi)).x;
    return ((unsigned)h << 16) | l;
}
__device__ __forceinline__ float bf_lo(unsigned u) {
    union { unsigned u; float f; } c; c.u = u << 16; return c.f;
}
__device__ __forceinline__ float bf_hi(unsigned u) {
    union { unsigned u; float f; } c; c.u = u & 0xffff0000u; return c.f;
}

// ---- coarse scatter: edges -> padded bucket-major staging ----------------
// In-block LDS counting sort, run-coalesced writes, direct range
// reservation in gcursor (no pre-histogram pass).
__global__ __launch_bounds__(256) void scatter_coarse(const int* __restrict__ ei,
                                                      const float* __restrict__ ew,
                                                      int* __restrict__ gcursor,
                                                      uint2* __restrict__ tmp) {
    __shared__ int hist[256];
    __shared__ int scan[256];
    __shared__ int lcur[256];
    __shared__ int adj[256];
    __shared__ uint2 rec[SC_EDGES];           // 32 KB
    __shared__ unsigned char bk[SC_EDGES];    // 4 KB
    int tid = threadIdx.x;
    hist[tid] = 0;
    __syncthreads();
    int base = blockIdx.x * SC_EDGES;
    unsigned ys[16];
    float    ws[16];
    int      bs[16];
    for (int i = 0; i < 16; ++i) {
        int e = base + i * 256 + tid;
        if (e < N_EDGES) {
            int t = ei[N_EDGES + e];
            bs[i] = t >> 9;
            ys[i] = (unsigned)ei[e] | ((unsigned)(t & 511) << 17);
            ws[i] = ew[e];
            atomicAdd(&hist[bs[i]], 1);
        } else bs[i] = -1;
    }
    __syncthreads();
    // exclusive scan of hist
    int v = hist[tid];
    scan[tid] = v;
    __syncthreads();
    for (int off = 1; off < 256; off <<= 1) {
        int t = scan[tid];
        int add = (tid >= off) ? scan[tid - off] : 0;
        __syncthreads();
        scan[tid] = t + add;
        __syncthreads();
    }
    int excl = scan[tid] - v;
    int gb = (v > 0) ? atomicAdd(&gcursor[tid], v) : 0;
    lcur[tid] = excl;
    adj[tid] = tid * CAP + gb - excl;  // global slot for LDS slot j: adj[b]+j
    __syncthreads();
    // place edges into LDS bucket-major
    for (int i = 0; i < 16; ++i) {
        if (bs[i] >= 0) {
            int j = atomicAdd(&lcur[bs[i]], 1);
            rec[j] = make_uint2(__float_as_uint(ws[i]), ys[i]);
            bk[j] = (unsigned char)bs[i];
        }
    }
    __syncthreads();
    // run-coalesced write-out
    int count = N_EDGES - base;
    if (count > SC_EDGES) count = SC_EDGES;
    for (int j = tid; j < count; j += 256) {
        int b = bk[j];
        tmp[adj[b] + j] = rec[j];
    }
}

// ---- exclusive scan of bucket counts -> dense ed bases -------------------
__global__ __launch_bounds__(256) void bucket_scan(const int* __restrict__ gcnt,
                                                   int* __restrict__ start) {
    __shared__ int s[256];
    int tid = threadIdx.x;
    int v = gcnt[tid];
    s[tid] = v;
    __syncthreads();
    for (int off = 1; off < 256; off <<= 1) {
        int t = s[tid];
        int add = (tid >= off) ? s[tid - off] : 0;
        __syncthreads();
        s[tid] = t + add;
        __syncthreads();
    }
    start[tid] = s[tid] - v;
    if (tid == 255) start[256] = s[255];   // == N_EDGES
}

// ---- per-bucket counting sort + rowptr + dis (one block per bucket) ------
__global__ __launch_bounds__(512) void fine_sort(const int* __restrict__ start,
                                                 const uint2* __restrict__ tmpPad,
                                                 int* __restrict__ rowptr,
                                                 float* __restrict__ dis,
                                                 EdgeRec* __restrict__ ed) {
    __shared__ int   cnt[512];
    __shared__ float wdeg[512];
    __shared__ int   s[512];
    int tid = threadIdx.x;
    int nodeBase = blockIdx.x << 9;
    int bb = start[blockIdx.x];
    int nEdge = start[blockIdx.x + 1] - bb;
    const uint2* tb = tmpPad + (size_t)blockIdx.x * CAP;
    cnt[tid] = 0;
    wdeg[tid] = 0.f;
    __syncthreads();
    for (int e = tid; e < nEdge; e += 512) {
        uint2 r = tb[e];
        int l = (r.y >> 17) & 511;
        atomicAdd(&cnt[l], 1);
        atomicAdd(&wdeg[l], __uint_as_float(r.x));
    }
    __syncthreads();
    int v = cnt[tid];
    s[tid] = v;
    __syncthreads();
    for (int off = 1; off < 512; off <<= 1) {
        int t = s[tid];
        int add = (tid >= off) ? s[tid - off] : 0;
        __syncthreads();
        s[tid] = t + add;
        __syncthreads();
    }
    int excl = s[tid] - v;
    int node = nodeBase + tid;
    if (node < N_NODES) {
        rowptr[node] = bb + excl;
        dis[node] = rsqrtf(wdeg[tid] + 1.0f);   // +1 = self-loop weight
    }
    if (node == N_NODES) rowptr[N_NODES] = N_EDGES;
    cnt[tid] = excl;       // reuse as cursor
    __syncthreads();
    for (int e = tid; e < nEdge; e += 512) {
        uint2 r = tb[e];
        int l = (r.y >> 17) & 511;
        int p = atomicAdd(&cnt[l], 1);
        EdgeRec o;
        o.s = (int)(r.y & 0x1FFFFu);
        o.v = __uint_as_float(r.x);
        ed[bb + p] = o;
    }
}

// ---- h = bf16( dis[row] * (x @ W1) )   [N,128] @ [128,64] ----------------
// dis-scaling folded: out[t] = dis_t*(sum w_e*h'[s_e] + h'[t]) + b, h'=dis.h
__global__ __launch_bounds__(256) void mm1_kernel(const float* __restrict__ x,
                                                  const float* __restrict__ W,
                                                  const float* __restrict__ dis,
                                                  unsigned* __restrict__ h) {
    __shared__ __align__(16) float xs[16][IN_C];      // 8 KB
    __shared__ __align__(16) float wsm[IN_C][HID_C];  // 32 KB
    int tid = threadIdx.x;
    {
        float4*       wd = (float4*)&wsm[0][0];
        const float4* wsrc = (const float4*)W;
        for (int i = tid; i < IN_C * HID_C / 4; i += 256) wd[i] = wsrc[i];
        float4*       xd = (float4*)&xs[0][0];
        const float4* xsrc = (const float4*)(x + (size_t)blockIdx.x * 16 * IN_C);
        for (int i = tid; i < 16 * IN_C / 4; i += 256) xd[i] = xsrc[i];
    }
    int rowBase = blockIdx.x * 16;
    __syncthreads();
    int c = tid & 63, rg = tid >> 6;
    const float4* xr0 = (const float4*)&xs[rg * 4 + 0][0];
    const float4* xr1 = (const float4*)&xs[rg * 4 + 1][0];
    const float4* xr2 = (const float4*)&xs[rg * 4 + 2][0];
    const float4* xr3 = (const float4*)&xs[rg * 4 + 3][0];
    float a0 = 0.f, a1 = 0.f, a2 = 0.f, a3 = 0.f;
    #pragma unroll 4
    for (int k4 = 0; k4 < IN_C / 4; ++k4) {
        float4 x0 = xr0[k4], x1 = xr1[k4], x2 = xr2[k4], x3 = xr3[k4];
        float w0 = wsm[4 * k4 + 0][c];
        float w1 = wsm[4 * k4 + 1][c];
        float w2 = wsm[4 * k4 + 2][c];
        float w3 = wsm[4 * k4 + 3][c];
        a0 += x0.x * w0 + x0.y * w1 + x0.z * w2 + x0.w * w3;
        a1 += x1.x * w0 + x1.y * w1 + x1.z * w2 + x1.w * w3;
        a2 += x2.x * w0 + x2.y * w1 + x2.z * w2 + x2.w * w3;
        a3 += x3.x * w0 + x3.y * w1 + x3.z * w2 + x3.w * w3;
    }
    a0 *= dis[rowBase + rg * 4 + 0];
    a1 *= dis[rowBase + rg * 4 + 1];
    a2 *= dis[rowBase + rg * 4 + 2];
    a3 *= dis[rowBase + rg * 4 + 3];
    float o0 = __shfl_xor(a0, 1, 64);
    float o1 = __shfl_xor(a1, 1, 64);
    float o2 = __shfl_xor(a2, 1, 64);
    float o3 = __shfl_xor(a3, 1, 64);
    if ((c & 1) == 0) {
        int ci = c >> 1;
        h[(rowBase + rg * 4 + 0) * 32 + ci] = pack_bf16(a0, o0);
        h[(rowBase + rg * 4 + 1) * 32 + ci] = pack_bf16(a1, o1);
        h[(rowBase + rg * 4 + 2) * 32 + ci] = pack_bf16(a2, o2);
        h[(rowBase + rg * 4 + 3) * 32 + ci] = pack_bf16(a3, o3);
    }
}

// ---- h = bf16( dis[row] * (a @ W2) )   [N,64] @ [64,64] ------------------
__global__ __launch_bounds__(256) void mm2_kernel(const float* __restrict__ a,
                                                  const float* __restrict__ W,
                                                  const float* __restrict__ dis,
                                                  unsigned* __restrict__ h) {
    __shared__ __align__(16) float as[16][HID_C];      // 4 KB
    __shared__ __align__(16) float wsm[HID_C][OUT_C];  // 16 KB
    int tid = threadIdx.x;
    {
        float4*       wd = (float4*)&wsm[0][0];
        const float4* wsrc = (const float4*)W;
        for (int i = tid; i < HID_C * OUT_C / 4; i += 256) wd[i] = wsrc[i];
        float4*       ad = (float4*)&as[0][0];
        const float4* asrc = (const float4*)(a + (size_t)blockIdx.x * 16 * HID_C);
        for (int i = tid; i < 16 * HID_C / 4; i += 256) ad[i] = asrc[i];
    }
    int rowBase = blockIdx.x * 16;
    __syncthreads();
    int c = tid & 63, rg = tid >> 6;
    const float4* xr0 = (const float4*)&as[rg * 4 + 0][0];
    const float4* xr1 = (const float4*)&as[rg * 4 + 1][0];
    const float4* xr2 = (const float4*)&as[rg * 4 + 2][0];
    const float4* xr3 = (const float4*)&as[rg * 4 + 3][0];
    float a0 = 0.f, a1 = 0.f, a2 = 0.f, a3 = 0.f;
    #pragma unroll 4
    for (int k4 = 0; k4 < HID_C / 4; ++k4) {
        float4 x0 = xr0[k4], x1 = xr1[k4], x2 = xr2[k4], x3 = xr3[k4];
        float w0 = wsm[4 * k4 + 0][c];
        float w1 = wsm[4 * k4 + 1][c];
        float w2 = wsm[4 * k4 + 2][c];
        float w3 = wsm[4 * k4 + 3][c];
        a0 += x0.x * w0 + x0.y * w1 + x0.z * w2 + x0.w * w3;
        a1 += x1.x * w0 + x1.y * w1 + x1.z * w2 + x1.w * w3;
        a2 += x2.x * w0 + x2.y * w1 + x2.z * w2 + x2.w * w3;
        a3 += x3.x * w0 + x3.y * w1 + x3.z * w2 + x3.w * w3;
    }
    a0 *= dis[rowBase + rg * 4 + 0];
    a1 *= dis[rowBase + rg * 4 + 1];
    a2 *= dis[rowBase + rg * 4 + 2];
    a3 *= dis[rowBase + rg * 4 + 3];
    float o0 = __shfl_xor(a0, 1, 64);
    float o1 = __shfl_xor(a1, 1, 64);
    float o2 = __shfl_xor(a2, 1, 64);
    float o3 = __shfl_xor(a3, 1, 64);
    if ((c & 1) == 0) {
        int ci = c >> 1;
        h[(rowBase + rg * 4 + 0) * 32 + ci] = pack_bf16(a0, o0);
        h[(rowBase + rg * 4 + 1) * 32 + ci] = pack_bf16(a1, o1);
        h[(rowBase + rg * 4 + 2) * 32 + ci] = pack_bf16(a2, o2);
        h[(rowBase + rg * 4 + 3) * 32 + ci] = pack_bf16(a3, o3);
    }
}

// ---- CSR aggregate + fused epilogue (bf16 dis-scaled h rows, 128 B) ------
// one wave per node; 8 groups of 8 lanes, one edge per group per step,
// lane reads uint4 = 8 bf16 channels. x4 unroll: 32 edges in flight.
__global__ __launch_bounds__(256) void agg_kernel(const int* __restrict__ rowptr,
                                                  const EdgeRec* __restrict__ ed,
                                                  const unsigned* __restrict__ h,
                                                  const float* __restrict__ dis,
                                                  const float* __restrict__ b,
                                                  float* __restrict__ out,
                                                  int relu) {
    int node = blockIdx.x * 4 + (threadIdx.x >> 6);
    int lane = threadIdx.x & 63;
    int g = lane >> 3;        // edge group 0..7
    int cl = lane & 7;        // channel octet: channels 8*cl .. 8*cl+7
    int beg = rowptr[node];
    int end = rowptr[node + 1];
    const uint4* h16 = (const uint4*)h;   // 8 uint4 per 64-ch row
    float acc[8] = {0.f, 0.f, 0.f, 0.f, 0.f, 0.f, 0.f, 0.f};
    int e = beg + g;
    for (; e + 24 < end; e += 32) {
        EdgeRec r0 = ed[e];
        EdgeRec r1 = ed[e + 8];
        EdgeRec r2 = ed[e + 16];
        EdgeRec r3 = ed[e + 24];
        uint4 u0 = h16[r0.s * 8 + cl];
        uint4 u1 = h16[r1.s * 8 + cl];
        uint4 u2 = h16[r2.s * 8 + cl];
        uint4 u3 = h16[r3.s * 8 + cl];
        acc[0] += r0.v * bf_lo(u0.x); acc[1] += r0.v * bf_hi(u0.x);
        acc[2] += r0.v * bf_lo(u0.y); acc[3] += r0.v * bf_hi(u0.y);
        acc[4] += r0.v * bf_lo(u0.z); acc[5] += r0.v * bf_hi(u0.z);
        acc[6] += r0.v * bf_lo(u0.w); acc[7] += r0.v * bf_hi(u0.w);
        acc[0] += r1.v * bf_lo(u1.x); acc[1] += r1.v * bf_hi(u1.x);
        acc[2] += r1.v * bf_lo(u1.y); acc[3] += r1.v * bf_hi(u1.y);
        acc[4] += r1.v * bf_lo(u1.z); acc[5] += r1.v * bf_hi(u1.z);
        acc[6] += r1.v * bf_lo(u1.w); acc[7] += r1.v * bf_hi(u1.w);
        acc[0] += r2.v * bf_lo(u2.x); acc[1] += r2.v * bf_hi(u2.x);
        acc[2] += r2.v * bf_lo(u2.y); acc[3] += r2.v * bf_hi(u2.y);
        acc[4] += r2.v * bf_lo(u2.z); acc[5] += r2.v * bf_hi(u2.z);
        acc[6] += r2.v * bf_lo(u2.w); acc[7] += r2.v * bf_hi(u2.w);
        acc[0] += r3.v * bf_lo(u3.x); acc[1] += r3.v * bf_hi(u3.x);
        acc[2] += r3.v * bf_lo(u3.y); acc[3] += r3.v * bf_hi(u3.y);
        acc[4] += r3.v * bf_lo(u3.z); acc[5] += r3.v * bf_hi(u3.z);
        acc[6] += r3.v * bf_lo(u3.w); acc[7] += r3.v * bf_hi(u3.w);
    }
    for (; e + 8 < end; e += 16) {
        EdgeRec r0 = ed[e];
        EdgeRec r1 = ed[e + 8];
        uint4 u0 = h16[r0.s * 8 + cl];
        uint4 u1 = h16[r1.s * 8 + cl];
        acc[0] += r0.v * bf_lo(u0.x); acc[1] += r0.v * bf_hi(u0.x);
        acc[2] += r0.v * bf_lo(u0.y); acc[3] += r0.v * bf_hi(u0.y);
        acc[4] += r0.v * bf_lo(u0.z); acc[5] += r0.v * bf_hi(u0.z);
        acc[6] += r0.v * bf_lo(u0.w); acc[7] += r0.v * bf_hi(u0.w);
        acc[0] += r1.v * bf_lo(u1.x); acc[1] += r1.v * bf_hi(u1.x);
        acc[2] += r1.v * bf_lo(u1.y); acc[3] += r1.v * bf_hi(u1.y);
        acc[4] += r1.v * bf_lo(u1.z); acc[5] += r1.v * bf_hi(u1.z);
        acc[6] += r1.v * bf_lo(u1.w); acc[7] += r1.v * bf_hi(u1.w);
    }
    if (e < end) {
        EdgeRec r0 = ed[e];
        uint4 u0 = h16[r0.s * 8 + cl];
        acc[0] += r0.v * bf_lo(u0.x); acc[1] += r0.v * bf_hi(u0.x);
        acc[2] += r0.v * bf_lo(u0.y); acc[3] += r0.v * bf_hi(u0.y);
        acc[4] += r0.v * bf_lo(u0.z); acc[5] += r0.v * bf_hi(u0.z);
        acc[6] += r0.v * bf_lo(u0.w); acc[7] += r0.v * bf_hi(u0.w);
    }
    #pragma unroll
    for (int k = 0; k < 8; ++k) {
        acc[k] += __shfl_xor(acc[k], 8, 64);
        acc[k] += __shfl_xor(acc[k], 16, 64);
        acc[k] += __shfl_xor(acc[k], 32, 64);
    }
    if (g == 0) {
        float d = dis[node];
        uint4 us = h16[node * 8 + cl];
        float hs[8] = { bf_lo(us.x), bf_hi(us.x), bf_lo(us.y), bf_hi(us.y),
                        bf_lo(us.z), bf_hi(us.z), bf_lo(us.w), bf_hi(us.w) };
        const float4* b4 = (const float4*)b;
        float4 bv0 = b4[cl * 2], bv1 = b4[cl * 2 + 1];
        float4 v0, v1;
        v0.x = d * (acc[0] + hs[0]) + bv0.x;
        v0.y = d * (acc[1] + hs[1]) + bv0.y;
        v0.z = d * (acc[2] + hs[2]) + bv0.z;
        v0.w = d * (acc[3] + hs[3]) + bv0.w;
        v1.x = d * (acc[4] + hs[4]) + bv1.x;
        v1.y = d * (acc[5] + hs[5]) + bv1.y;
        v1.z = d * (acc[6] + hs[6]) + bv1.z;
        v1.w = d * (acc[7] + hs[7]) + bv1.w;
        if (relu) {
            v0.x = fmaxf(v0.x, 0.f); v0.y = fmaxf(v0.y, 0.f);
            v0.z = fmaxf(v0.z, 0.f); v0.w = fmaxf(v0.w, 0.f);
            v1.x = fmaxf(v1.x, 0.f); v1.y = fmaxf(v1.y, 0.f);
            v1.z = fmaxf(v1.z, 0.f); v1.w = fmaxf(v1.w, 0.f);
        }
        float4* o4 = (float4*)out;
        o4[node * 16 + cl * 2]     = v0;
        o4[node * 16 + cl * 2 + 1] = v1;
    }
}

extern "C" void kernel_launch(void* const* d_in, const int* in_sizes, int n_in,
                              void* d_out, int out_size, void* d_ws, size_t ws_size,
                              hipStream_t stream) {
    const float* x  = (const float*)d_in[0];
    const int*   ei = (const int*)d_in[1];   // [2, E]: sources then targets
    const float* ew = (const float*)d_in[2];
    const float* W1 = (const float*)d_in[3];
    const float* b1 = (const float*)d_in[4];
    const float* W2 = (const float*)d_in[5];
    const float* b2 = (const float*)d_in[6];
    float* out = (float*)d_out;

    // workspace carve-up (256 B aligned). tmpPad (28.9 MB, padded buckets)
    // is dead after fine_sort; bf16 h (12.8 MB) + f32 a (25.6 MB) overlay it.
    char* p = (char*)d_ws;
    auto carve = [&](size_t bytes) { char* r = p; p += (bytes + 255) & ~(size_t)255; return r; };
    float*    dis     = (float*)carve(N_NODES * 4);
    int*      rowptr  = (int*)carve((N_NODES + 1) * 4);
    int*      start   = (int*)carve(257 * 4);
    int*      gcursor = (int*)carve(256 * 4);
    EdgeRec*  ed      = (EdgeRec*)carve((size_t)N_EDGES * 8);
    size_t    r2sz    = (size_t)NBUCKET * CAP * 8;                 // 28.9 MB
    size_t    hasz    = (size_t)N_NODES * 64 * 6;                  // 38.4 MB
    char*     r2      = carve(r2sz > hasz ? r2sz : hasz);
    uint2*    tmpPad  = (uint2*)r2;
    unsigned* h       = (unsigned*)r2;                             // 12.8 MB
    float*    a       = (float*)(r2 + (size_t)N_NODES * 64 * 2);   // 25.6 MB

    // --- CSR build: direct padded reservation, no pre-histogram ---
    hipMemsetAsync(gcursor, 0, 256 * sizeof(int), stream);
    scatter_coarse<<<SC_GRID, 256, 0, stream>>>(ei, ew, gcursor, tmpPad);
    bucket_scan<<<1, 256, 0, stream>>>(gcursor, start);
    fine_sort<<<NBUCKET, 512, 0, stream>>>(start, tmpPad, rowptr, dis, ed);

    // --- layer 1: h = bf16(dis.(x@W1)) ; a = relu(agg(h) + b1) ---
    mm1_kernel<<<N_NODES / 16, 256, 0, stream>>>(x, W1, dis, h);
    agg_kernel<<<N_NODES / 4, 256, 0, stream>>>(rowptr, ed, h, dis, b1, a, 1);

    // --- layer 2: h = bf16(dis.(a@W2)) ; out = agg(h) + b2 ---
    mm2_kernel<<<N_NODES / 16, 256, 0, stream>>>(a, W2, dis, h);
    agg_kernel<<<N_NODES / 4, 256, 0, stream>>>(rowptr, ed, h, dis, b2, out, 0);
}